// Round 2
// baseline (14399.657 us; speedup 1.0000x reference)
//
#include <hip/hip_runtime.h>
#include <hip/hip_bf16.h>
#include <math.h>

#define D 512
#define NNODES 10000
#define NEDGES 80000
#define LAYERS 5
#define EPS 1e-5f

typedef __bf16 bf16x8 __attribute__((ext_vector_type(8)));
typedef float f32x4 __attribute__((ext_vector_type(4)));

// ---------- bf16 split helpers ----------
__device__ inline unsigned short f2bf(float x) {
  unsigned u = __float_as_uint(x);
  unsigned r = u + 0x7fffu + ((u >> 16) & 1u);
  return (unsigned short)(r >> 16);
}
__device__ inline float bf2f(unsigned short h) { return __uint_as_float(((unsigned)h) << 16); }
__device__ inline void split2(float x, unsigned short& h, unsigned short& l) {
  h = f2bf(x);
  l = f2bf(x - bf2f(h));
}
__device__ inline uint4 pack8(const unsigned short* v) {
  uint4 r;
  r.x = (unsigned)v[0] | ((unsigned)v[1] << 16);
  r.y = (unsigned)v[2] | ((unsigned)v[3] << 16);
  r.z = (unsigned)v[4] | ((unsigned)v[5] << 16);
  r.w = (unsigned)v[6] | ((unsigned)v[7] << 16);
  return r;
}
__device__ inline void unpack8(uint4 v, unsigned short* o) {
  o[0] = v.x & 0xffff; o[1] = v.x >> 16;
  o[2] = v.y & 0xffff; o[3] = v.y >> 16;
  o[4] = v.z & 0xffff; o[5] = v.z >> 16;
  o[6] = v.w & 0xffff; o[7] = v.w >> 16;
}

// ordered-float keys for atomicMax
__device__ inline unsigned fkey(float f) {
  unsigned b = __float_as_uint(f);
  return (b & 0x80000000u) ? ~b : (b | 0x80000000u);
}
__device__ inline float funkey(unsigned k) {
  unsigned b = (k & 0x80000000u) ? (k ^ 0x80000000u) : ~k;
  return __uint_as_float(b);
}

__device__ inline void gload16(const void* g, void* l) {
  __builtin_amdgcn_global_load_lds((const __attribute__((address_space(1))) void*)g,
                                   (__attribute__((address_space(3))) void*)l, 16, 0, 0);
}

// ---------------------------------------------------------------------------
// I-format: for a logical f32 [R][512] activation, row r occupies 2048 bytes.
// Octet o (cols 8o..8o+7): 32 bytes at r*2048 + o*32. hi-bf16x8 (16B) at slot
// ((r&1)<<4), lo-bf16x8 at the other slot (XOR 16). The row-parity swizzle
// makes gemm ds_read_b128 hit all 8 bank-groups uniformly.
// ---------------------------------------------------------------------------

// split f32 -> I-format (src may == dst for in-place)
__global__ __launch_bounds__(256) void splitI_k(const float* __restrict__ src,
                                                char* __restrict__ dst, int nOct) {
  for (long long i = (long long)blockIdx.x * 256 + threadIdx.x; i < nOct;
       i += (long long)gridDim.x * 256) {
    int row = (int)(i >> 6), oct = (int)(i & 63);
    const float* s = src + (size_t)row * 512 + oct * 8;
    float4 x0 = *(const float4*)s, x1 = *(const float4*)(s + 4);
    float xs[8] = {x0.x, x0.y, x0.z, x0.w, x1.x, x1.y, x1.z, x1.w};
    unsigned short h[8], l[8];
#pragma unroll
    for (int j = 0; j < 8; j++) split2(xs[j], h[j], l[j]);
    char* base = dst + (size_t)row * 2048 + oct * 32;
    int ph = (row & 1) << 4;
    *(uint4*)(base + ph) = pack8(h);
    *(uint4*)(base + (ph ^ 16)) = pack8(l);
  }
}

// z2 = z2raw/(z+eps), then split to I-format in place over z2
__global__ __launch_bounds__(256) void divsplitI_k(float* __restrict__ z2,
                                                   const float* __restrict__ z, int nOct) {
  for (long long i = (long long)blockIdx.x * 256 + threadIdx.x; i < nOct;
       i += (long long)gridDim.x * 256) {
    int row = (int)(i >> 6), oct = (int)(i & 63);
    float* s = z2 + (size_t)row * 512 + oct * 8;
    const float* zp = z + (size_t)row * 512 + oct * 8;
    float xs[8];
#pragma unroll
    for (int j = 0; j < 8; j++) xs[j] = s[j] / (zp[j] + EPS);
    unsigned short h[8], l[8];
#pragma unroll
    for (int j = 0; j < 8; j++) split2(xs[j], h[j], l[j]);
    char* base = (char*)z2 + (size_t)row * 2048 + oct * 32;
    int ph = (row & 1) << 4;
    *(uint4*)(base + ph) = pack8(h);
    *(uint4*)(base + (ph ^ 16)) = pack8(l);
  }
}

// weight prep: W[1024][512] f32 (15 mats) -> WT[n=512][k=1024] I-format (4096B rows)
__global__ __launch_bounds__(256) void wprep_k(const float* __restrict__ Wa,
                                               const float* __restrict__ Wn,
                                               const float* __restrict__ We,
                                               char* __restrict__ WT) {
  __shared__ float tile[64][65];
  int mat = blockIdx.z;
  const float* W = (mat < 5) ? Wa + (size_t)mat * 1024 * 512
                 : (mat < 10) ? Wn + (size_t)(mat - 5) * 1024 * 512
                              : We + (size_t)(mat - 10) * 1024 * 512;
  char* out = WT + (size_t)mat * 512 * 1024 * 4;
  int n0 = blockIdx.x * 64, k0 = blockIdx.y * 64;
  int t = threadIdx.x;
  int ty = t >> 2, tx = t & 3;
  const float* wr = W + (size_t)(k0 + ty) * 512 + n0 + tx * 16;
  float4 v0 = *(const float4*)(wr + 0), v1 = *(const float4*)(wr + 4);
  float4 v2 = *(const float4*)(wr + 8), v3 = *(const float4*)(wr + 12);
  float vv[16] = {v0.x, v0.y, v0.z, v0.w, v1.x, v1.y, v1.z, v1.w,
                  v2.x, v2.y, v2.z, v2.w, v3.x, v3.y, v3.z, v3.w};
#pragma unroll
  for (int j = 0; j < 16; j++) tile[ty][tx * 16 + j] = vv[j];
  __syncthreads();
#pragma unroll
  for (int p = 0; p < 2; p++) {
    int chunk = t + p * 256;       // 0..511
    int n = chunk >> 3, cc = chunk & 7;
    float xs[8];
#pragma unroll
    for (int j = 0; j < 8; j++) xs[j] = tile[cc * 8 + j][n];
    unsigned short h[8], l[8];
#pragma unroll
    for (int j = 0; j < 8; j++) split2(xs[j], h[j], l[j]);
    int ng = n0 + n;
    int kc = (k0 >> 3) + cc;
    char* b = out + (size_t)ng * 4096 + kc * 32;
    int ph = (ng & 1) << 4;
    *(uint4*)(b + ph) = pack8(h);
    *(uint4*)(b + (ph ^ 16)) = pack8(l);
  }
}

// ---------------------------------------------------------------------------
// GEMM: Y[R][512] f32 = X@W via 3-term bf16 split MFMA.
// X: I-format rows (2048B). KT=1024: k<512 from X1, k>=512 from X2.
// W: WT I-format [512][1024] (4096B rows), B chunk base cb0.
// ---------------------------------------------------------------------------
template<int KT, bool ACT>
__global__ __launch_bounds__(256) void gemmI(const char* __restrict__ X1,
                                             const char* __restrict__ X2,
                                             const char* __restrict__ BW, int cb0,
                                             float* __restrict__ Y, int R) {
  __shared__ char smem[32768];
  char* As = smem;
  char* Bs = smem + 16384;
  const int tid = threadIdx.x;
  const int lane = tid & 63, wv = tid >> 6;
  const int bn0 = blockIdx.x * 128, bm0 = blockIdx.y * 128;
  const int r16 = lane & 15, g = lane >> 4;
  const int mo = (wv >> 1) * 64, no = (wv & 1) * 64;
  const int lr = lane >> 3, ls = (lane & 7) * 16;
  f32x4 acc[4][4];
#pragma unroll
  for (int i = 0; i < 4; i++)
#pragma unroll
    for (int j = 0; j < 4; j++) acc[i][j] = (f32x4){0.f, 0.f, 0.f, 0.f};

  for (int kt = 0; kt < KT; kt += 32) {
    const char* ab;
    int acb;
    if (KT == 1024 && kt >= 512) { ab = X2; acb = (kt - 512) >> 3; }
    else { ab = X1; acb = kt >> 3; }
#pragma unroll
    for (int i = 0; i < 4; i++) {
      int rb = i * 4 + wv;
      int grow = bm0 + rb * 8 + lr;
      if (grow > R - 1) grow = R - 1;
      gload16(ab + (size_t)grow * 2048 + acb * 32 + ls, As + rb * 1024);
    }
    int bcb = cb0 + (kt >> 3);
#pragma unroll
    for (int i = 0; i < 4; i++) {
      int rb = i * 4 + wv;
      int nrow = bn0 + rb * 8 + lr;
      gload16(BW + (size_t)nrow * 4096 + bcb * 32 + ls, Bs + rb * 1024);
    }
    __syncthreads();
    bf16x8 ah[4], al[4], bh[4], bl[4];
#pragma unroll
    for (int mi = 0; mi < 4; mi++) {
      int row = mo + mi * 16 + r16;
      int off = row * 128 + g * 32 + ((row & 1) << 4);
      ah[mi] = *(const bf16x8*)(As + off);
      al[mi] = *(const bf16x8*)(As + (off ^ 16));
    }
#pragma unroll
    for (int ni = 0; ni < 4; ni++) {
      int row = no + ni * 16 + r16;
      int off = row * 128 + g * 32 + ((row & 1) << 4);
      bh[ni] = *(const bf16x8*)(Bs + off);
      bl[ni] = *(const bf16x8*)(Bs + (off ^ 16));
    }
#pragma unroll
    for (int mi = 0; mi < 4; mi++)
#pragma unroll
      for (int ni = 0; ni < 4; ni++) {
        acc[mi][ni] = __builtin_amdgcn_mfma_f32_16x16x32_bf16(ah[mi], bh[ni], acc[mi][ni], 0, 0, 0);
        acc[mi][ni] = __builtin_amdgcn_mfma_f32_16x16x32_bf16(ah[mi], bl[ni], acc[mi][ni], 0, 0, 0);
        acc[mi][ni] = __builtin_amdgcn_mfma_f32_16x16x32_bf16(al[mi], bh[ni], acc[mi][ni], 0, 0, 0);
      }
    __syncthreads();
  }
  // epilogue: C/D layout col=lane&15, row=(lane>>4)*4+reg
#pragma unroll
  for (int mi = 0; mi < 4; mi++)
#pragma unroll
    for (int j = 0; j < 4; j++) {
      int row = bm0 + mo + mi * 16 + g * 4 + j;
      if (row < R) {
#pragma unroll
        for (int ni = 0; ni < 4; ni++) {
          float v = acc[mi][ni][j];
          if (ACT) v = (v >= 0.f) ? v : 0.01f * v;
          Y[(size_t)row * 512 + bn0 + no + ni * 16 + r16] = v;
        }
      }
    }
}

// ---------------------------------------------------------------------------
// column maxes of sp = Ea + Na[dst], sr = Ea + Na[src]  (round-1 proven)
// ---------------------------------------------------------------------------
__global__ __launch_bounds__(256) void colmax_k(const float* __restrict__ Ea,
                                                const float* __restrict__ Na,
                                                const int* __restrict__ src,
                                                const int* __restrict__ dst,
                                                unsigned* __restrict__ mp,
                                                unsigned* __restrict__ mr) {
  const int t = threadIdx.x;
  float p0 = -1e30f, p1 = -1e30f, r0 = -1e30f, r1 = -1e30f;
  for (int e = blockIdx.x; e < NEDGES; e += gridDim.x) {
    int d = dst[e], s = src[e];
    const float* ea = Ea + (size_t)e * D;
    const float* nd = Na + (size_t)d * D;
    const float* ns = Na + (size_t)s * D;
    float e0 = ea[t], e1 = ea[t + 256];
    p0 = fmaxf(p0, e0 + nd[t]);  p1 = fmaxf(p1, e1 + nd[t + 256]);
    r0 = fmaxf(r0, e0 + ns[t]);  r1 = fmaxf(r1, e1 + ns[t + 256]);
  }
  atomicMax(&mp[t], fkey(p0));  atomicMax(&mp[t + 256], fkey(p1));
  atomicMax(&mr[t], fkey(r0));  atomicMax(&mr[t + 256], fkey(r1));
}

// ---------------------------------------------------------------------------
// fused edge pass: z += ap; z2raw += ap*ex; blend -> I-format (bout may == Ea)
// block = 4 edges x 64 octets; one wave handles one edge (coalesced rows)
// ---------------------------------------------------------------------------
__global__ __launch_bounds__(256) void edgepass_k(const float* __restrict__ Ea,
                                                  const float* __restrict__ Na,
                                                  const char* __restrict__ exI,
                                                  const char* __restrict__ nxI,
                                                  const int* __restrict__ src,
                                                  const int* __restrict__ dst,
                                                  const unsigned* __restrict__ mp,
                                                  const unsigned* __restrict__ mr,
                                                  float* __restrict__ z,
                                                  float* __restrict__ z2,
                                                  char* __restrict__ bout) {
  const int t = threadIdx.x, g = t >> 6, o = t & 63;
  float m_p[8], m_r[8];
#pragma unroll
  for (int j = 0; j < 8; j++) {
    m_p[j] = funkey(mp[o * 8 + j]);
    m_r[j] = funkey(mr[o * 8 + j]);
  }
  for (int e0 = blockIdx.x * 4; e0 < NEDGES; e0 += gridDim.x * 4) {
    int e = e0 + g;
    int d = dst[e], s = src[e];
    const float* ea = Ea + (size_t)e * 512 + o * 8;
    float4 a0 = *(const float4*)ea, a1 = *(const float4*)(ea + 4);
    const float* nd = Na + (size_t)d * 512 + o * 8;
    float4 d0 = *(const float4*)nd, d1 = *(const float4*)(nd + 4);
    const float* ns = Na + (size_t)s * 512 + o * 8;
    float4 s0 = *(const float4*)ns, s1 = *(const float4*)(ns + 4);
    const char* xb = exI + (size_t)e * 2048 + o * 32;
    int phe = (e & 1) << 4;
    unsigned short xh[8], xl[8];
    unpack8(*(const uint4*)(xb + phe), xh);
    unpack8(*(const uint4*)(xb + (phe ^ 16)), xl);
    const char* ndb = nxI + (size_t)d * 2048 + o * 32;
    int phd = (d & 1) << 4;
    unsigned short dh[8], dl[8];
    unpack8(*(const uint4*)(ndb + phd), dh);
    unpack8(*(const uint4*)(ndb + (phd ^ 16)), dl);
    const char* nsb = nxI + (size_t)s * 2048 + o * 32;
    int phs = (s & 1) << 4;
    unsigned short sh[8], sl[8];
    unpack8(*(const uint4*)(nsb + phs), sh);
    unpack8(*(const uint4*)(nsb + (phs ^ 16)), sl);
    float eav[8] = {a0.x, a0.y, a0.z, a0.w, a1.x, a1.y, a1.z, a1.w};
    float ndv[8] = {d0.x, d0.y, d0.z, d0.w, d1.x, d1.y, d1.z, d1.w};
    float nsv[8] = {s0.x, s0.y, s0.z, s0.w, s1.x, s1.y, s1.z, s1.w};
    float* zp = z + (size_t)d * 512 + o * 8;
    float* z2p = z2 + (size_t)d * 512 + o * 8;
    unsigned short bh[8], bl2[8];
#pragma unroll
    for (int j = 0; j < 8; j++) {
      float sp = eav[j] + ndv[j] - m_p[j];
      float sr = eav[j] + nsv[j] - m_r[j];
      float ap = __expf(sp);
      float xe = bf2f(xh[j]) + bf2f(xl[j]);
      atomicAdd(&zp[j], ap);
      atomicAdd(&z2p[j], ap * xe);
      float u = sr - sp;
      float wr;
      if (u >= 0.f) { float ev = __expf(-u); wr = 1.f / (1.f + ev); }
      else          { float ev = __expf(u);  wr = ev / (1.f + ev); }
      float xd_ = bf2f(dh[j]) + bf2f(dl[j]);
      float xs_ = bf2f(sh[j]) + bf2f(sl[j]);
      split2(wr * xs_ + (1.f - wr) * xd_, bh[j], bl2[j]);
    }
    char* ob = bout + (size_t)e * 2048 + o * 32;
    *(uint4*)(ob + phe) = pack8(bh);
    *(uint4*)(ob + (phe ^ 16)) = pack8(bl2);
  }
}

// node_conf = nx @ Wnc ([512,55])
__global__ __launch_bounds__(256) void nodeconf_k(const float* __restrict__ nx,
                                                  const float* __restrict__ Wnc,
                                                  float* __restrict__ out) {
  int w = threadIdx.x >> 6, lane = threadIdx.x & 63;
  int n = blockIdx.x * 4 + w;
  const float* r = nx + (size_t)n * D;
  if (lane < 55) {
    float acc = 0.f;
    for (int k = 0; k < D; k++) acc = fmaf(r[k], Wnc[k * 55 + lane], acc);
    out[(size_t)n * 55 + lane] = acc;
  }
}

// edge_conf = ex @ Wec ([512,2])
__global__ __launch_bounds__(256) void edgeconf_k(const float* __restrict__ ex,
                                                  const float* __restrict__ Wec,
                                                  float* __restrict__ out) {
  int w = threadIdx.x >> 6, lane = threadIdx.x & 63;
  int e = blockIdx.x * 4 + w;
  const float* r = ex + (size_t)e * D;
  float a0 = 0.f, a1 = 0.f;
#pragma unroll
  for (int j = 0; j < 8; j++) {
    int c = lane + j * 64;
    float x = r[c];
    a0 = fmaf(x, Wec[c * 2 + 0], a0);
    a1 = fmaf(x, Wec[c * 2 + 1], a1);
  }
#pragma unroll
  for (int off = 32; off; off >>= 1) {
    a0 += __shfl_down(a0, off);
    a1 += __shfl_down(a1, off);
  }
  if (lane == 0) { out[(size_t)e * 2 + 0] = a0; out[(size_t)e * 2 + 1] = a1; }
}

extern "C" void kernel_launch(void* const* d_in, const int* in_sizes, int n_in,
                              void* d_out, int out_size, void* d_ws, size_t ws_size,
                              hipStream_t stream) {
  const float* in_nx = (const float*)d_in[0];
  const float* in_ex = (const float*)d_in[1];
  const int* src = (const int*)d_in[2];
  const int* dst = (const int*)d_in[3];
  const float* Wa = (const float*)d_in[4];
  const float* Wn = (const float*)d_in[5];
  const float* We = (const float*)d_in[6];
  const float* Wnc = (const float*)d_in[7];
  const float* Wec = (const float*)d_in[8];

  float* out = (float*)d_out;
  float* o_nx = out;
  float* o_nc = o_nx + (size_t)NNODES * D;
  float* o_ex = o_nc + (size_t)NNODES * 55;
  float* o_ec = o_ex + (size_t)NEDGES * D;

  const size_t SZ_E = (size_t)NEDGES * 2048;   // 163.84 MB
  const size_t SZ_N = (size_t)NNODES * 2048;   // 20.48 MB
  const size_t MATSZ = (size_t)512 * 1024 * 4; // 2 MB
  char* w = (char*)d_ws;
  float* P1 = (float*)w;                 // Ea f32 / blendI (l=4) / edge-gemm out
  char* P0 = w + SZ_E;                   // exI
  char* nxI = w + 2 * SZ_E;              // nx I-format
  float* Na = (float*)(w + 2 * SZ_E + SZ_N);
  float* z  = (float*)(w + 2 * SZ_E + 2 * SZ_N);
  float* z2 = (float*)(w + 2 * SZ_E + 3 * SZ_N);
  unsigned* mp = (unsigned*)(w + 2 * SZ_E + 4 * SZ_N);
  char* WT = w + 2 * SZ_E + 4 * SZ_N + 8192;

  // weight transpose + split (15 mats), input activations -> I-format
  wprep_k<<<dim3(8, 16, 15), 256, 0, stream>>>(Wa, Wn, We, WT);
  splitI_k<<<2048, 256, 0, stream>>>(in_ex, P0, NEDGES * 64);
  splitI_k<<<2048, 256, 0, stream>>>(in_nx, nxI, NNODES * 64);

  dim3 gE(4, NEDGES / 128);            // (4, 625)
  dim3 gN(4, (NNODES + 127) / 128);    // (4, 79)

  for (int l = 0; l < LAYERS; l++) {
    const char* WaT = WT + (size_t)l * MATSZ;
    const char* WnT = WT + (size_t)(5 + l) * MATSZ;
    const char* WeT = WT + (size_t)(10 + l) * MATSZ;

    hipMemsetAsync(z, 0, 2 * SZ_N + 4096, stream);  // z, z2, mp, mr

    // Ea = ex @ Wa_top ; Na = nx @ Wa_bot
    gemmI<512, false><<<gE, 256, 0, stream>>>(P0, nullptr, WaT, 0, P1, NEDGES);
    gemmI<512, false><<<gN, 256, 0, stream>>>(nxI, nullptr, WaT, 64, Na, NNODES);

    colmax_k<<<2048, 256, 0, stream>>>(P1, Na, src, dst, mp, mp + 512);

    char* blendDst = (l < 4) ? (char*)o_ex : (char*)P1;
    edgepass_k<<<2048, 256, 0, stream>>>(P1, Na, P0, nxI, src, dst, mp, mp + 512,
                                         z, z2, blendDst);
    divsplitI_k<<<2048, 256, 0, stream>>>(z2, z, NNODES * 64);

    // node update: nx' = act(concat(z2, nx) @ Wn) -> o_nx f32
    gemmI<1024, true><<<gN, 256, 0, stream>>>((char*)z2, nxI, WnT, 0, o_nx, NNODES);
    if (l < 4) splitI_k<<<2048, 256, 0, stream>>>(o_nx, nxI, NNODES * 64);

    // edge update: ex' = act(concat(blend, ex) @ We)
    float* edgeOut = (l < 4) ? P1 : o_ex;
    gemmI<1024, true><<<gE, 256, 0, stream>>>(blendDst, P0, WeT, 0, edgeOut, NEDGES);
    if (l < 4) splitI_k<<<2048, 256, 0, stream>>>(P1, P0, NEDGES * 64);
  }

  nodeconf_k<<<NNODES / 4, 256, 0, stream>>>(o_nx, Wnc, o_nc);
  edgeconf_k<<<NEDGES / 4, 256, 0, stream>>>(o_ex, Wec, o_ec);
}

// Round 3
// 7397.675 us; speedup vs baseline: 1.9465x; 1.9465x over previous
//
#include <hip/hip_runtime.h>
#include <hip/hip_bf16.h>
#include <math.h>

#define D 512
#define NNODES 10000
#define NEDGES 80000
#define LAYERS 5
#define EPS 1e-5f

typedef __bf16 bf16x8 __attribute__((ext_vector_type(8)));
typedef float f32x4 __attribute__((ext_vector_type(4)));

// ---------- bf16 split helpers ----------
__device__ inline unsigned short f2bf(float x) {
  unsigned u = __float_as_uint(x);
  unsigned r = u + 0x7fffu + ((u >> 16) & 1u);
  return (unsigned short)(r >> 16);
}
__device__ inline float bf2f(unsigned short h) { return __uint_as_float(((unsigned)h) << 16); }
__device__ inline void split2(float x, unsigned short& h, unsigned short& l) {
  h = f2bf(x);
  l = f2bf(x - bf2f(h));
}
__device__ inline uint4 pack8(const unsigned short* v) {
  uint4 r;
  r.x = (unsigned)v[0] | ((unsigned)v[1] << 16);
  r.y = (unsigned)v[2] | ((unsigned)v[3] << 16);
  r.z = (unsigned)v[4] | ((unsigned)v[5] << 16);
  r.w = (unsigned)v[6] | ((unsigned)v[7] << 16);
  return r;
}
__device__ inline void unpack8(uint4 v, unsigned short* o) {
  o[0] = v.x & 0xffff; o[1] = v.x >> 16;
  o[2] = v.y & 0xffff; o[3] = v.y >> 16;
  o[4] = v.z & 0xffff; o[5] = v.z >> 16;
  o[6] = v.w & 0xffff; o[7] = v.w >> 16;
}

// ordered-float keys for atomicMax
__device__ inline unsigned fkey(float f) {
  unsigned b = __float_as_uint(f);
  return (b & 0x80000000u) ? ~b : (b | 0x80000000u);
}
__device__ inline float funkey(unsigned k) {
  unsigned b = (k & 0x80000000u) ? (k ^ 0x80000000u) : ~k;
  return __uint_as_float(b);
}

__device__ inline void gload16(const void* g, void* l) {
  __builtin_amdgcn_global_load_lds((const __attribute__((address_space(1))) void*)g,
                                   (__attribute__((address_space(3))) void*)l, 16, 0, 0);
}

// ---------------------------------------------------------------------------
// I-format: logical f32 [R][512] activation, row r occupies 2048 bytes.
// Octet o (cols 8o..8o+7): 32 bytes at r*2048 + o*32; hi-bf16x8 at slot
// ((r&1)<<4), lo-bf16x8 at the other slot (XOR 16).
// ---------------------------------------------------------------------------

// split f32 -> I-format (input prep only)
__global__ __launch_bounds__(256) void splitI_k(const float* __restrict__ src,
                                                char* __restrict__ dst, int nOct) {
  for (long long i = (long long)blockIdx.x * 256 + threadIdx.x; i < nOct;
       i += (long long)gridDim.x * 256) {
    int row = (int)(i >> 6), oct = (int)(i & 63);
    const float* s = src + (size_t)row * 512 + oct * 8;
    float4 x0 = *(const float4*)s, x1 = *(const float4*)(s + 4);
    float xs[8] = {x0.x, x0.y, x0.z, x0.w, x1.x, x1.y, x1.z, x1.w};
    unsigned short h[8], l[8];
#pragma unroll
    for (int j = 0; j < 8; j++) split2(xs[j], h[j], l[j]);
    char* base = dst + (size_t)row * 2048 + oct * 32;
    int ph = (row & 1) << 4;
    *(uint4*)(base + ph) = pack8(h);
    *(uint4*)(base + (ph ^ 16)) = pack8(l);
  }
}

// weight prep: W[1024][512] f32 (15 mats) -> WT[n=512][k=1024] I-format rows
__global__ __launch_bounds__(256) void wprep_k(const float* __restrict__ Wa,
                                               const float* __restrict__ Wn,
                                               const float* __restrict__ We,
                                               char* __restrict__ WT) {
  __shared__ float tile[64][65];
  int mat = blockIdx.z;
  const float* W = (mat < 5) ? Wa + (size_t)mat * 1024 * 512
                 : (mat < 10) ? Wn + (size_t)(mat - 5) * 1024 * 512
                              : We + (size_t)(mat - 10) * 1024 * 512;
  char* out = WT + (size_t)mat * 512 * 1024 * 4;
  int n0 = blockIdx.x * 64, k0 = blockIdx.y * 64;
  int t = threadIdx.x;
  int ty = t >> 2, tx = t & 3;
  const float* wr = W + (size_t)(k0 + ty) * 512 + n0 + tx * 16;
  float4 v0 = *(const float4*)(wr + 0), v1 = *(const float4*)(wr + 4);
  float4 v2 = *(const float4*)(wr + 8), v3 = *(const float4*)(wr + 12);
  float vv[16] = {v0.x, v0.y, v0.z, v0.w, v1.x, v1.y, v1.z, v1.w,
                  v2.x, v2.y, v2.z, v2.w, v3.x, v3.y, v3.z, v3.w};
#pragma unroll
  for (int j = 0; j < 16; j++) tile[ty][tx * 16 + j] = vv[j];
  __syncthreads();
#pragma unroll
  for (int p = 0; p < 2; p++) {
    int chunk = t + p * 256;
    int n = chunk >> 3, cc = chunk & 7;
    float xs[8];
#pragma unroll
    for (int j = 0; j < 8; j++) xs[j] = tile[cc * 8 + j][n];
    unsigned short h[8], l[8];
#pragma unroll
    for (int j = 0; j < 8; j++) split2(xs[j], h[j], l[j]);
    int ng = n0 + n;
    int kc = (k0 >> 3) + cc;
    char* b = out + (size_t)ng * 4096 + kc * 32;
    int ph = (ng & 1) << 4;
    *(uint4*)(b + ph) = pack8(h);
    *(uint4*)(b + (ph ^ 16)) = pack8(l);
  }
}

// ---------------------------------------------------------------------------
// CSR build over dst (dst fixed across layers)
// ---------------------------------------------------------------------------
__global__ __launch_bounds__(256) void hist_k(const int* __restrict__ dst, int* __restrict__ cnt) {
  int e = blockIdx.x * 256 + threadIdx.x;
  if (e < NEDGES) atomicAdd(&cnt[dst[e]], 1);
}

__global__ __launch_bounds__(256) void scan_k(const int* __restrict__ cnt,
                                              int* __restrict__ off, int* __restrict__ cur) {
  __shared__ int part[256];
  const int CH = (NNODES + 255) / 256;
  int t = threadIdx.x;
  int s = 0;
  int l0 = t * CH;
  for (int i = 0; i < CH; i++) {
    int idx = l0 + i;
    if (idx < NNODES) s += cnt[idx];
  }
  part[t] = s;
  __syncthreads();
  if (t == 0) {
    int acc = 0;
    for (int i = 0; i < 256; i++) { int v = part[i]; part[i] = acc; acc += v; }
  }
  __syncthreads();
  int acc = part[t];
  for (int i = 0; i < CH; i++) {
    int idx = l0 + i;
    if (idx < NNODES) { off[idx] = acc; cur[idx] = acc; acc += cnt[idx]; }
  }
  if (t == 255) off[NNODES] = acc;
}

__global__ __launch_bounds__(256) void scatter_k(const int* __restrict__ dst,
                                                 int* __restrict__ cur, int* __restrict__ eid) {
  int e = blockIdx.x * 256 + threadIdx.x;
  if (e < NEDGES) {
    int p = atomicAdd(&cur[dst[e]], 1);
    eid[p] = e;
  }
}

// ---------------------------------------------------------------------------
// GEMM: Y[R][512] = X@W via 3-term bf16 split MFMA. OUT_I: write I-format.
// ---------------------------------------------------------------------------
template<int KT, bool ACT, bool OUT_I>
__global__ __launch_bounds__(256) void gemmI(const char* __restrict__ X1,
                                             const char* __restrict__ X2,
                                             const char* __restrict__ BW, int cb0,
                                             void* __restrict__ Yout, int R) {
  __shared__ char smem[32768];
  char* As = smem;
  char* Bs = smem + 16384;
  const int tid = threadIdx.x;
  const int lane = tid & 63, wv = tid >> 6;
  const int bn0 = blockIdx.x * 128, bm0 = blockIdx.y * 128;
  const int r16 = lane & 15, g = lane >> 4;
  const int mo = (wv >> 1) * 64, no = (wv & 1) * 64;
  const int lr = lane >> 3, ls = (lane & 7) * 16;
  f32x4 acc[4][4];
#pragma unroll
  for (int i = 0; i < 4; i++)
#pragma unroll
    for (int j = 0; j < 4; j++) acc[i][j] = (f32x4){0.f, 0.f, 0.f, 0.f};

  for (int kt = 0; kt < KT; kt += 32) {
    const char* ab;
    int acb;
    if (KT == 1024 && kt >= 512) { ab = X2; acb = (kt - 512) >> 3; }
    else { ab = X1; acb = kt >> 3; }
#pragma unroll
    for (int i = 0; i < 4; i++) {
      int rb = i * 4 + wv;
      int grow = bm0 + rb * 8 + lr;
      if (grow > R - 1) grow = R - 1;
      gload16(ab + (size_t)grow * 2048 + acb * 32 + ls, As + rb * 1024);
    }
    int bcb = cb0 + (kt >> 3);
#pragma unroll
    for (int i = 0; i < 4; i++) {
      int rb = i * 4 + wv;
      int nrow = bn0 + rb * 8 + lr;
      gload16(BW + (size_t)nrow * 4096 + bcb * 32 + ls, Bs + rb * 1024);
    }
    __syncthreads();
    bf16x8 ah[4], al[4], bh[4], bl[4];
#pragma unroll
    for (int mi = 0; mi < 4; mi++) {
      int row = mo + mi * 16 + r16;
      int off = row * 128 + g * 32 + ((row & 1) << 4);
      ah[mi] = *(const bf16x8*)(As + off);
      al[mi] = *(const bf16x8*)(As + (off ^ 16));
    }
#pragma unroll
    for (int ni = 0; ni < 4; ni++) {
      int row = no + ni * 16 + r16;
      int off = row * 128 + g * 32 + ((row & 1) << 4);
      bh[ni] = *(const bf16x8*)(Bs + off);
      bl[ni] = *(const bf16x8*)(Bs + (off ^ 16));
    }
#pragma unroll
    for (int mi = 0; mi < 4; mi++)
#pragma unroll
      for (int ni = 0; ni < 4; ni++) {
        acc[mi][ni] = __builtin_amdgcn_mfma_f32_16x16x32_bf16(ah[mi], bh[ni], acc[mi][ni], 0, 0, 0);
        acc[mi][ni] = __builtin_amdgcn_mfma_f32_16x16x32_bf16(ah[mi], bl[ni], acc[mi][ni], 0, 0, 0);
        acc[mi][ni] = __builtin_amdgcn_mfma_f32_16x16x32_bf16(al[mi], bh[ni], acc[mi][ni], 0, 0, 0);
      }
    __syncthreads();
  }

  if (!OUT_I) {
    float* Y = (float*)Yout;
#pragma unroll
    for (int mi = 0; mi < 4; mi++)
#pragma unroll
      for (int j = 0; j < 4; j++) {
        int row = bm0 + mo + mi * 16 + g * 4 + j;
        if (row < R) {
#pragma unroll
          for (int ni = 0; ni < 4; ni++) {
            float v = acc[mi][ni][j];
            if (ACT) v = (v >= 0.f) ? v : 0.01f * v;
            Y[(size_t)row * 512 + bn0 + no + ni * 16 + r16] = v;
          }
        }
      }
  } else {
    // LDS-staged I-format epilogue, two 64-row halves
    float* stg = (float*)smem;
#pragma unroll
    for (int h = 0; h < 2; h++) {
      __syncthreads();
      if ((wv >> 1) == h) {
#pragma unroll
        for (int mi = 0; mi < 4; mi++)
#pragma unroll
          for (int j = 0; j < 4; j++) {
            int rl = mi * 16 + g * 4 + j;
#pragma unroll
            for (int ni = 0; ni < 4; ni++) {
              float v = acc[mi][ni][j];
              if (ACT) v = (v >= 0.f) ? v : 0.01f * v;
              stg[rl * 128 + no + ni * 16 + r16] = v;
            }
          }
      }
      __syncthreads();
#pragma unroll
      for (int q = 0; q < 4; q++) {
        int idx = tid + q * 256;
        int rl = idx >> 4, oc = idx & 15;
        int grow = bm0 + h * 64 + rl;
        if (grow < R) {
          float xs[8];
#pragma unroll
          for (int j = 0; j < 8; j++) xs[j] = stg[rl * 128 + oc * 8 + j];
          unsigned short hh[8], ll[8];
#pragma unroll
          for (int j = 0; j < 8; j++) split2(xs[j], hh[j], ll[j]);
          char* ob = (char*)Yout + (size_t)grow * 2048 + ((bn0 >> 3) + oc) * 32;
          int ph = (grow & 1) << 4;
          *(uint4*)(ob + ph) = pack8(hh);
          *(uint4*)(ob + (ph ^ 16)) = pack8(ll);
        }
      }
    }
  }
}

// ---------------------------------------------------------------------------
// colmax: mp[c]=max_e(Ea[e,c]+Na[dst[e],c]), mr with src. Octet-per-lane.
// ---------------------------------------------------------------------------
__global__ __launch_bounds__(256) void colmax2_k(const float* __restrict__ Ea,
                                                 const float* __restrict__ Na,
                                                 const int* __restrict__ src,
                                                 const int* __restrict__ dst,
                                                 unsigned* __restrict__ mp,
                                                 unsigned* __restrict__ mr) {
  const int g = threadIdx.x >> 6, o = threadIdx.x & 63;
  float pm[8], rm[8];
#pragma unroll
  for (int j = 0; j < 8; j++) { pm[j] = -1e30f; rm[j] = -1e30f; }
  for (int e = blockIdx.x * 4 + g; e < NEDGES; e += gridDim.x * 4) {
    int d = dst[e], s = src[e];
    const float* ea = Ea + (size_t)e * 512 + o * 8;
    float4 a0 = *(const float4*)ea, a1 = *(const float4*)(ea + 4);
    const float* nd = Na + (size_t)d * 512 + o * 8;
    float4 d0 = *(const float4*)nd, d1 = *(const float4*)(nd + 4);
    const float* ns = Na + (size_t)s * 512 + o * 8;
    float4 s0 = *(const float4*)ns, s1 = *(const float4*)(ns + 4);
    float ev[8] = {a0.x, a0.y, a0.z, a0.w, a1.x, a1.y, a1.z, a1.w};
    float dv[8] = {d0.x, d0.y, d0.z, d0.w, d1.x, d1.y, d1.z, d1.w};
    float sv[8] = {s0.x, s0.y, s0.z, s0.w, s1.x, s1.y, s1.z, s1.w};
#pragma unroll
    for (int j = 0; j < 8; j++) {
      pm[j] = fmaxf(pm[j], ev[j] + dv[j]);
      rm[j] = fmaxf(rm[j], ev[j] + sv[j]);
    }
  }
#pragma unroll
  for (int j = 0; j < 8; j++) {
    atomicMax(&mp[o * 8 + j], fkey(pm[j]));
    atomicMax(&mr[o * 8 + j], fkey(rm[j]));
  }
}

// ---------------------------------------------------------------------------
// aggblend: per node n (one wave): z,z2 in regs over CSR in-edges; writes
// blend I-format in-place over Ea rows; tail writes z2I = split(z2/(z+eps)).
// ---------------------------------------------------------------------------
__global__ __launch_bounds__(256) void aggblend_k(float* __restrict__ EaB,
                                                  const float* __restrict__ Na,
                                                  const char* __restrict__ exI,
                                                  const char* __restrict__ nxI,
                                                  const int* __restrict__ src,
                                                  const int* __restrict__ off,
                                                  const int* __restrict__ eid,
                                                  const unsigned* __restrict__ mp,
                                                  const unsigned* __restrict__ mr,
                                                  char* __restrict__ z2I) {
  const int w = threadIdx.x >> 6, o = threadIdx.x & 63;
  int n = blockIdx.x * 4 + w;
  if (n >= NNODES) return;
  float m_p[8], m_r[8], nd[8], xd[8], z[8], z2[8];
#pragma unroll
  for (int j = 0; j < 8; j++) {
    m_p[j] = funkey(mp[o * 8 + j]);
    m_r[j] = funkey(mr[o * 8 + j]);
    z[j] = 0.f; z2[j] = 0.f;
  }
  {
    const float* np = Na + (size_t)n * 512 + o * 8;
    float4 d0 = *(const float4*)np, d1 = *(const float4*)(np + 4);
    nd[0] = d0.x; nd[1] = d0.y; nd[2] = d0.z; nd[3] = d0.w;
    nd[4] = d1.x; nd[5] = d1.y; nd[6] = d1.z; nd[7] = d1.w;
    const char* xb = nxI + (size_t)n * 2048 + o * 32;
    int ph = (n & 1) << 4;
    unsigned short hh[8], ll[8];
    unpack8(*(const uint4*)(xb + ph), hh);
    unpack8(*(const uint4*)(xb + (ph ^ 16)), ll);
#pragma unroll
    for (int j = 0; j < 8; j++) xd[j] = bf2f(hh[j]) + bf2f(ll[j]);
  }
  const int i0 = off[n], i1 = off[n + 1];
  for (int i = i0; i < i1; i++) {
    int e = eid[i];
    int s = src[e];
    float* ea = EaB + (size_t)e * 512 + o * 8;
    float4 a0 = *(const float4*)ea, a1 = *(const float4*)(ea + 4);
    const float* ns = Na + (size_t)s * 512 + o * 8;
    float4 s0 = *(const float4*)ns, s1 = *(const float4*)(ns + 4);
    int phe = (e & 1) << 4;
    const char* xb = exI + (size_t)e * 2048 + o * 32;
    unsigned short xh[8], xl[8];
    unpack8(*(const uint4*)(xb + phe), xh);
    unpack8(*(const uint4*)(xb + (phe ^ 16)), xl);
    int phs = (s & 1) << 4;
    const char* sb = nxI + (size_t)s * 2048 + o * 32;
    unsigned short sh[8], sl[8];
    unpack8(*(const uint4*)(sb + phs), sh);
    unpack8(*(const uint4*)(sb + (phs ^ 16)), sl);
    float ev[8] = {a0.x, a0.y, a0.z, a0.w, a1.x, a1.y, a1.z, a1.w};
    float sv[8] = {s0.x, s0.y, s0.z, s0.w, s1.x, s1.y, s1.z, s1.w};
    unsigned short bh[8], bl2[8];
#pragma unroll
    for (int j = 0; j < 8; j++) {
      float sp = ev[j] + nd[j] - m_p[j];
      float sr = ev[j] + sv[j] - m_r[j];
      float ap = __expf(sp);
      float xe = bf2f(xh[j]) + bf2f(xl[j]);
      z[j] += ap;
      z2[j] += ap * xe;
      float u = sr - sp;
      float evx = __expf(-fabsf(u));
      float wpos = 1.f / (1.f + evx);
      float wr = (u >= 0.f) ? wpos : 1.f - wpos;
      float xs_ = bf2f(sh[j]) + bf2f(sl[j]);
      split2(wr * xs_ + (1.f - wr) * xd[j], bh[j], bl2[j]);
    }
    char* ob = (char*)EaB + (size_t)e * 2048 + o * 32;
    *(uint4*)(ob + phe) = pack8(bh);
    *(uint4*)(ob + (phe ^ 16)) = pack8(bl2);
  }
  unsigned short zh[8], zl[8];
#pragma unroll
  for (int j = 0; j < 8; j++) split2(z2[j] / (z[j] + EPS), zh[j], zl[j]);
  char* zb = z2I + (size_t)n * 2048 + o * 32;
  int phn = (n & 1) << 4;
  *(uint4*)(zb + phn) = pack8(zh);
  *(uint4*)(zb + (phn ^ 16)) = pack8(zl);
}

// node_conf = nx @ Wnc ([512,55])
__global__ __launch_bounds__(256) void nodeconf_k(const float* __restrict__ nx,
                                                  const float* __restrict__ Wnc,
                                                  float* __restrict__ out) {
  int w = threadIdx.x >> 6, lane = threadIdx.x & 63;
  int n = blockIdx.x * 4 + w;
  const float* r = nx + (size_t)n * D;
  if (lane < 55) {
    float acc = 0.f;
    for (int k = 0; k < D; k++) acc = fmaf(r[k], Wnc[k * 55 + lane], acc);
    out[(size_t)n * 55 + lane] = acc;
  }
}

// edge_conf = ex @ Wec ([512,2])
__global__ __launch_bounds__(256) void edgeconf_k(const float* __restrict__ ex,
                                                  const float* __restrict__ Wec,
                                                  float* __restrict__ out) {
  int w = threadIdx.x >> 6, lane = threadIdx.x & 63;
  int e = blockIdx.x * 4 + w;
  const float* r = ex + (size_t)e * D;
  float a0 = 0.f, a1 = 0.f;
#pragma unroll
  for (int j = 0; j < 8; j++) {
    int c = lane + j * 64;
    float x = r[c];
    a0 = fmaf(x, Wec[c * 2 + 0], a0);
    a1 = fmaf(x, Wec[c * 2 + 1], a1);
  }
#pragma unroll
  for (int off = 32; off; off >>= 1) {
    a0 += __shfl_down(a0, off);
    a1 += __shfl_down(a1, off);
  }
  if (lane == 0) { out[(size_t)e * 2 + 0] = a0; out[(size_t)e * 2 + 1] = a1; }
}

extern "C" void kernel_launch(void* const* d_in, const int* in_sizes, int n_in,
                              void* d_out, int out_size, void* d_ws, size_t ws_size,
                              hipStream_t stream) {
  const float* in_nx = (const float*)d_in[0];
  const float* in_ex = (const float*)d_in[1];
  const int* src = (const int*)d_in[2];
  const int* dst = (const int*)d_in[3];
  const float* Wa = (const float*)d_in[4];
  const float* Wn = (const float*)d_in[5];
  const float* We = (const float*)d_in[6];
  const float* Wnc = (const float*)d_in[7];
  const float* Wec = (const float*)d_in[8];

  float* out = (float*)d_out;
  float* o_nx = out;
  float* o_nc = o_nx + (size_t)NNODES * D;
  float* o_ex = o_nc + (size_t)NNODES * 55;
  float* o_ec = o_ex + (size_t)NEDGES * D;

  const size_t SZ_E = (size_t)NEDGES * 2048;   // 163.84 MB
  const size_t SZ_N = (size_t)NNODES * 2048;   // 20.48 MB
  const size_t MATSZ = (size_t)512 * 1024 * 4; // 2 MB
  char* w = (char*)d_ws;
  float* P1 = (float*)w;                        // Ea f32 -> blendI (in place)
  char* exA = w + SZ_E;                         // exI ping
  char* nxA = w + 2 * SZ_E;                     // nxI ping
  float* Na = (float*)(w + 2 * SZ_E + SZ_N);
  char* z2I = w + 2 * SZ_E + 2 * SZ_N;
  unsigned* mp = (unsigned*)(w + 2 * SZ_E + 3 * SZ_N);   // mp[512], mr[512]
  char* WT = w + 2 * SZ_E + 3 * SZ_N + 8192;
  char* csr = WT + 15 * MATSZ;
  int* cnt = (int*)csr;                          // NNODES
  int* offp = cnt + NNODES + 8;                  // NNODES+1
  int* cur = offp + NNODES + 8;
  int* eid = cur + NNODES + 8;                   // NEDGES

  char* exB = (char*)o_ex;   // 160 MB region, ping-pong
  char* nxB = (char*)o_nx;   // 20.48 MB region, ping-pong

  // one-time prep
  wprep_k<<<dim3(8, 16, 15), 256, 0, stream>>>(Wa, Wn, We, WT);
  splitI_k<<<2048, 256, 0, stream>>>(in_ex, exA, NEDGES * 64);
  splitI_k<<<2048, 256, 0, stream>>>(in_nx, nxA, NNODES * 64);
  hipMemsetAsync(cnt, 0, NNODES * sizeof(int), stream);
  hist_k<<<(NEDGES + 255) / 256, 256, 0, stream>>>(dst, cnt);
  scan_k<<<1, 256, 0, stream>>>(cnt, offp, cur);
  scatter_k<<<(NEDGES + 255) / 256, 256, 0, stream>>>(dst, cur, eid);

  dim3 gE(4, NEDGES / 128);           // (4, 625)
  dim3 gN(4, (NNODES + 127) / 128);   // (4, 79)

  for (int l = 0; l < LAYERS; l++) {
    const char* WaT = WT + (size_t)l * MATSZ;
    const char* WnT = WT + (size_t)(5 + l) * MATSZ;
    const char* WeT = WT + (size_t)(10 + l) * MATSZ;
    char* exCur = (l & 1) ? exB : exA;
    char* exNxt = (l & 1) ? exA : exB;
    char* nxCur = (l & 1) ? nxB : nxA;
    char* nxNxt = (l & 1) ? nxA : nxB;

    hipMemsetAsync(mp, 0, 4096, stream);  // mp, mr -> fkey(-inf)-equivalent

    // Na = nx @ Wa_bot ; Ea = ex @ Wa_top
    gemmI<512, false, false><<<gN, 256, 0, stream>>>(nxCur, nullptr, WaT, 64, Na, NNODES);
    gemmI<512, false, false><<<gE, 256, 0, stream>>>(exCur, nullptr, WaT, 0, P1, NEDGES);

    colmax2_k<<<1024, 256, 0, stream>>>(P1, Na, src, dst, mp, mp + 512);

    aggblend_k<<<(NNODES + 3) / 4, 256, 0, stream>>>(P1, Na, exCur, nxCur, src,
                                                     offp, eid, mp, mp + 512, z2I);

    // node update: nx' = act(concat(z2, nx) @ Wn)
    if (l < 4)
      gemmI<1024, true, true><<<gN, 256, 0, stream>>>(z2I, nxCur, WnT, 0, nxNxt, NNODES);
    else
      gemmI<1024, true, false><<<gN, 256, 0, stream>>>(z2I, nxCur, WnT, 0, o_nx, NNODES);

    // edge update: ex' = act(concat(blend, ex) @ We)
    if (l < 4)
      gemmI<1024, true, true><<<gE, 256, 0, stream>>>((char*)P1, exCur, WeT, 0, exNxt, NEDGES);
    else
      gemmI<1024, true, false><<<gE, 256, 0, stream>>>((char*)P1, exCur, WeT, 0, o_ex, NEDGES);
  }

  nodeconf_k<<<NNODES / 4, 256, 0, stream>>>(o_nx, Wnc, o_nc);
  edgeconf_k<<<NEDGES / 4, 256, 0, stream>>>(o_ex, Wec, o_ec);
}

// Round 4
// 4372.010 us; speedup vs baseline: 3.2936x; 1.6921x over previous
//
#include <hip/hip_runtime.h>
#include <hip/hip_bf16.h>
#include <math.h>

#define D 512
#define NNODES 10000
#define NEDGES 80000
#define LAYERS 5
#define EPS 1e-5f

typedef __bf16 bf16x8 __attribute__((ext_vector_type(8)));
typedef float f32x4 __attribute__((ext_vector_type(4)));

// ---------- bf16 split helpers ----------
__device__ inline unsigned short f2bf(float x) {
  unsigned u = __float_as_uint(x);
  unsigned r = u + 0x7fffu + ((u >> 16) & 1u);
  return (unsigned short)(r >> 16);
}
__device__ inline float bf2f(unsigned short h) { return __uint_as_float(((unsigned)h) << 16); }
__device__ inline void split2(float x, unsigned short& h, unsigned short& l) {
  h = f2bf(x);
  l = f2bf(x - bf2f(h));
}
__device__ inline uint4 pack8(const unsigned short* v) {
  uint4 r;
  r.x = (unsigned)v[0] | ((unsigned)v[1] << 16);
  r.y = (unsigned)v[2] | ((unsigned)v[3] << 16);
  r.z = (unsigned)v[4] | ((unsigned)v[5] << 16);
  r.w = (unsigned)v[6] | ((unsigned)v[7] << 16);
  return r;
}
__device__ inline void unpack8(uint4 v, unsigned short* o) {
  o[0] = v.x & 0xffff; o[1] = v.x >> 16;
  o[2] = v.y & 0xffff; o[3] = v.y >> 16;
  o[4] = v.z & 0xffff; o[5] = v.z >> 16;
  o[6] = v.w & 0xffff; o[7] = v.w >> 16;
}

__device__ inline void gload16(const void* g, void* l) {
  __builtin_amdgcn_global_load_lds((const __attribute__((address_space(1))) void*)g,
                                   (__attribute__((address_space(3))) void*)l, 16, 0, 0);
}

// ---------------------------------------------------------------------------
// I-format: logical f32 [R][512] activation, row r occupies 2048 bytes.
// Octet o (cols 8o..8o+7): 32 bytes at r*2048 + o*32; hi-bf16x8 at slot
// ((r&1)<<4), lo-bf16x8 at the other slot (XOR 16).
// ---------------------------------------------------------------------------

// split f32 -> I-format (input prep only)
__global__ __launch_bounds__(256) void splitI_k(const float* __restrict__ src,
                                                char* __restrict__ dst, int nOct) {
  for (long long i = (long long)blockIdx.x * 256 + threadIdx.x; i < nOct;
       i += (long long)gridDim.x * 256) {
    int row = (int)(i >> 6), oct = (int)(i & 63);
    const float* s = src + (size_t)row * 512 + oct * 8;
    float4 x0 = *(const float4*)s, x1 = *(const float4*)(s + 4);
    float xs[8] = {x0.x, x0.y, x0.z, x0.w, x1.x, x1.y, x1.z, x1.w};
    unsigned short h[8], l[8];
#pragma unroll
    for (int j = 0; j < 8; j++) split2(xs[j], h[j], l[j]);
    char* base = dst + (size_t)row * 2048 + oct * 32;
    int ph = (row & 1) << 4;
    *(uint4*)(base + ph) = pack8(h);
    *(uint4*)(base + (ph ^ 16)) = pack8(l);
  }
}

// weight prep: W[1024][512] f32 (15 mats) -> WT[n=512][k=1024] I-format rows
__global__ __launch_bounds__(256) void wprep_k(const float* __restrict__ Wa,
                                               const float* __restrict__ Wn,
                                               const float* __restrict__ We,
                                               char* __restrict__ WT) {
  __shared__ float tile[64][65];
  int mat = blockIdx.z;
  const float* W = (mat < 5) ? Wa + (size_t)mat * 1024 * 512
                 : (mat < 10) ? Wn + (size_t)(mat - 5) * 1024 * 512
                              : We + (size_t)(mat - 10) * 1024 * 512;
  char* out = WT + (size_t)mat * 512 * 1024 * 4;
  int n0 = blockIdx.x * 64, k0 = blockIdx.y * 64;
  int t = threadIdx.x;
  int ty = t >> 2, tx = t & 3;
  const float* wr = W + (size_t)(k0 + ty) * 512 + n0 + tx * 16;
  float4 v0 = *(const float4*)(wr + 0), v1 = *(const float4*)(wr + 4);
  float4 v2 = *(const float4*)(wr + 8), v3 = *(const float4*)(wr + 12);
  float vv[16] = {v0.x, v0.y, v0.z, v0.w, v1.x, v1.y, v1.z, v1.w,
                  v2.x, v2.y, v2.z, v2.w, v3.x, v3.y, v3.z, v3.w};
#pragma unroll
  for (int j = 0; j < 16; j++) tile[ty][tx * 16 + j] = vv[j];
  __syncthreads();
#pragma unroll
  for (int p = 0; p < 2; p++) {
    int chunk = t + p * 256;
    int n = chunk >> 3, cc = chunk & 7;
    float xs[8];
#pragma unroll
    for (int j = 0; j < 8; j++) xs[j] = tile[cc * 8 + j][n];
    unsigned short h[8], l[8];
#pragma unroll
    for (int j = 0; j < 8; j++) split2(xs[j], h[j], l[j]);
    int ng = n0 + n;
    int kc = (k0 >> 3) + cc;
    char* b = out + (size_t)ng * 4096 + kc * 32;
    int ph = (ng & 1) << 4;
    *(uint4*)(b + ph) = pack8(h);
    *(uint4*)(b + (ph ^ 16)) = pack8(l);
  }
}

// ---------------------------------------------------------------------------
// CSR build over dst (dst fixed across layers)
// ---------------------------------------------------------------------------
__global__ __launch_bounds__(256) void hist_k(const int* __restrict__ dst, int* __restrict__ cnt) {
  int e = blockIdx.x * 256 + threadIdx.x;
  if (e < NEDGES) atomicAdd(&cnt[dst[e]], 1);
}

__global__ __launch_bounds__(256) void scan_k(const int* __restrict__ cnt,
                                              int* __restrict__ off, int* __restrict__ cur) {
  __shared__ int part[256];
  const int CH = (NNODES + 255) / 256;
  int t = threadIdx.x;
  int s = 0;
  int l0 = t * CH;
  for (int i = 0; i < CH; i++) {
    int idx = l0 + i;
    if (idx < NNODES) s += cnt[idx];
  }
  part[t] = s;
  __syncthreads();
  if (t == 0) {
    int acc = 0;
    for (int i = 0; i < 256; i++) { int v = part[i]; part[i] = acc; acc += v; }
  }
  __syncthreads();
  int acc = part[t];
  for (int i = 0; i < CH; i++) {
    int idx = l0 + i;
    if (idx < NNODES) { off[idx] = acc; cur[idx] = acc; acc += cnt[idx]; }
  }
  if (t == 255) off[NNODES] = acc;
}

__global__ __launch_bounds__(256) void scatter_k(const int* __restrict__ dst,
                                                 int* __restrict__ cur, int* __restrict__ eid) {
  int e = blockIdx.x * 256 + threadIdx.x;
  if (e < NEDGES) {
    int p = atomicAdd(&cur[dst[e]], 1);
    eid[p] = e;
  }
}

// ---------------------------------------------------------------------------
// GEMM: Y[R][512] = X@W via 3-term bf16 split MFMA. OUT_I: write I-format.
// ---------------------------------------------------------------------------
template<int KT, bool ACT, bool OUT_I>
__global__ __launch_bounds__(256) void gemmI(const char* __restrict__ X1,
                                             const char* __restrict__ X2,
                                             const char* __restrict__ BW, int cb0,
                                             void* __restrict__ Yout, int R) {
  __shared__ char smem[32768];
  char* As = smem;
  char* Bs = smem + 16384;
  const int tid = threadIdx.x;
  const int lane = tid & 63, wv = tid >> 6;
  const int bn0 = blockIdx.x * 128, bm0 = blockIdx.y * 128;
  const int r16 = lane & 15, g = lane >> 4;
  const int mo = (wv >> 1) * 64, no = (wv & 1) * 64;
  const int lr = lane >> 3, ls = (lane & 7) * 16;
  f32x4 acc[4][4];
#pragma unroll
  for (int i = 0; i < 4; i++)
#pragma unroll
    for (int j = 0; j < 4; j++) acc[i][j] = (f32x4){0.f, 0.f, 0.f, 0.f};

  for (int kt = 0; kt < KT; kt += 32) {
    const char* ab;
    int acb;
    if (KT == 1024 && kt >= 512) { ab = X2; acb = (kt - 512) >> 3; }
    else { ab = X1; acb = kt >> 3; }
#pragma unroll
    for (int i = 0; i < 4; i++) {
      int rb = i * 4 + wv;
      int grow = bm0 + rb * 8 + lr;
      if (grow > R - 1) grow = R - 1;
      gload16(ab + (size_t)grow * 2048 + acb * 32 + ls, As + rb * 1024);
    }
    int bcb = cb0 + (kt >> 3);
#pragma unroll
    for (int i = 0; i < 4; i++) {
      int rb = i * 4 + wv;
      int nrow = bn0 + rb * 8 + lr;
      gload16(BW + (size_t)nrow * 4096 + bcb * 32 + ls, Bs + rb * 1024);
    }
    __syncthreads();
    bf16x8 ah[4], al[4], bh[4], bl[4];
#pragma unroll
    for (int mi = 0; mi < 4; mi++) {
      int row = mo + mi * 16 + r16;
      int off = row * 128 + g * 32 + ((row & 1) << 4);
      ah[mi] = *(const bf16x8*)(As + off);
      al[mi] = *(const bf16x8*)(As + (off ^ 16));
    }
#pragma unroll
    for (int ni = 0; ni < 4; ni++) {
      int row = no + ni * 16 + r16;
      int off = row * 128 + g * 32 + ((row & 1) << 4);
      bh[ni] = *(const bf16x8*)(Bs + off);
      bl[ni] = *(const bf16x8*)(Bs + (off ^ 16));
    }
#pragma unroll
    for (int mi = 0; mi < 4; mi++)
#pragma unroll
      for (int ni = 0; ni < 4; ni++) {
        acc[mi][ni] = __builtin_amdgcn_mfma_f32_16x16x32_bf16(ah[mi], bh[ni], acc[mi][ni], 0, 0, 0);
        acc[mi][ni] = __builtin_amdgcn_mfma_f32_16x16x32_bf16(ah[mi], bl[ni], acc[mi][ni], 0, 0, 0);
        acc[mi][ni] = __builtin_amdgcn_mfma_f32_16x16x32_bf16(al[mi], bh[ni], acc[mi][ni], 0, 0, 0);
      }
    __syncthreads();
  }

  if (!OUT_I) {
    float* Y = (float*)Yout;
#pragma unroll
    for (int mi = 0; mi < 4; mi++)
#pragma unroll
      for (int j = 0; j < 4; j++) {
        int row = bm0 + mo + mi * 16 + g * 4 + j;
        if (row < R) {
#pragma unroll
          for (int ni = 0; ni < 4; ni++) {
            float v = acc[mi][ni][j];
            if (ACT) v = (v >= 0.f) ? v : 0.01f * v;
            Y[(size_t)row * 512 + bn0 + no + ni * 16 + r16] = v;
          }
        }
      }
  } else {
    // LDS-staged I-format epilogue, two 64-row halves
    float* stg = (float*)smem;
#pragma unroll
    for (int h = 0; h < 2; h++) {
      __syncthreads();
      if ((wv >> 1) == h) {
#pragma unroll
        for (int mi = 0; mi < 4; mi++)
#pragma unroll
          for (int j = 0; j < 4; j++) {
            int rl = mi * 16 + g * 4 + j;
#pragma unroll
            for (int ni = 0; ni < 4; ni++) {
              float v = acc[mi][ni][j];
              if (ACT) v = (v >= 0.f) ? v : 0.01f * v;
              stg[rl * 128 + no + ni * 16 + r16] = v;
            }
          }
      }
      __syncthreads();
#pragma unroll
      for (int q = 0; q < 4; q++) {
        int idx = tid + q * 256;
        int rl = idx >> 4, oc = idx & 15;
        int grow = bm0 + h * 64 + rl;
        if (grow < R) {
          float xs[8];
#pragma unroll
          for (int j = 0; j < 8; j++) xs[j] = stg[rl * 128 + oc * 8 + j];
          unsigned short hh[8], ll[8];
#pragma unroll
          for (int j = 0; j < 8; j++) split2(xs[j], hh[j], ll[j]);
          char* ob = (char*)Yout + (size_t)grow * 2048 + ((bn0 >> 3) + oc) * 32;
          int ph = (grow & 1) << 4;
          *(uint4*)(ob + ph) = pack8(hh);
          *(uint4*)(ob + (ph ^ 16)) = pack8(ll);
        }
      }
    }
  }
}

// ---------------------------------------------------------------------------
// colmax stage 1: per-block partial column maxes, no atomics.
// grid 1024 x 256: wave g handles edges base, base+1 (2 indep chains), stride 8192.
// ---------------------------------------------------------------------------
__global__ __launch_bounds__(256) void colmax_part_k(const float* __restrict__ Ea,
                                                     const float* __restrict__ Na,
                                                     const int* __restrict__ src,
                                                     const int* __restrict__ dst,
                                                     float* __restrict__ part_p,
                                                     float* __restrict__ part_r) {
  __shared__ float sP[4][512];
  __shared__ float sR[4][512];
  const int g = threadIdx.x >> 6, o = threadIdx.x & 63;
  float pm[8], rm[8];
#pragma unroll
  for (int j = 0; j < 8; j++) { pm[j] = -1e30f; rm[j] = -1e30f; }
  for (int e = blockIdx.x * 8 + g * 2; e < NEDGES; e += 8192) {
    // two independent edges: e (even) and e+1 (< NEDGES since NEDGES even)
    int dA = dst[e], sA = src[e], dB = dst[e + 1], sB = src[e + 1];
    const float* eaA = Ea + (size_t)e * 512 + o * 8;
    const float* eaB = Ea + (size_t)(e + 1) * 512 + o * 8;
    float4 aA0 = *(const float4*)eaA, aA1 = *(const float4*)(eaA + 4);
    float4 aB0 = *(const float4*)eaB, aB1 = *(const float4*)(eaB + 4);
    const float* ndA = Na + (size_t)dA * 512 + o * 8;
    const float* nsA = Na + (size_t)sA * 512 + o * 8;
    const float* ndB = Na + (size_t)dB * 512 + o * 8;
    const float* nsB = Na + (size_t)sB * 512 + o * 8;
    float4 dA0 = *(const float4*)ndA, dA1 = *(const float4*)(ndA + 4);
    float4 sA0 = *(const float4*)nsA, sA1 = *(const float4*)(nsA + 4);
    float4 dB0 = *(const float4*)ndB, dB1 = *(const float4*)(ndB + 4);
    float4 sB0 = *(const float4*)nsB, sB1 = *(const float4*)(nsB + 4);
    float eA[8] = {aA0.x, aA0.y, aA0.z, aA0.w, aA1.x, aA1.y, aA1.z, aA1.w};
    float eB[8] = {aB0.x, aB0.y, aB0.z, aB0.w, aB1.x, aB1.y, aB1.z, aB1.w};
    float dvA[8] = {dA0.x, dA0.y, dA0.z, dA0.w, dA1.x, dA1.y, dA1.z, dA1.w};
    float svA[8] = {sA0.x, sA0.y, sA0.z, sA0.w, sA1.x, sA1.y, sA1.z, sA1.w};
    float dvB[8] = {dB0.x, dB0.y, dB0.z, dB0.w, dB1.x, dB1.y, dB1.z, dB1.w};
    float svB[8] = {sB0.x, sB0.y, sB0.z, sB0.w, sB1.x, sB1.y, sB1.z, sB1.w};
#pragma unroll
    for (int j = 0; j < 8; j++) {
      pm[j] = fmaxf(pm[j], fmaxf(eA[j] + dvA[j], eB[j] + dvB[j]));
      rm[j] = fmaxf(rm[j], fmaxf(eA[j] + svA[j], eB[j] + svB[j]));
    }
  }
#pragma unroll
  for (int j = 0; j < 8; j++) { sP[g][o * 8 + j] = pm[j]; sR[g][o * 8 + j] = rm[j]; }
  __syncthreads();
  for (int c = threadIdx.x; c < 512; c += 256) {
    float v = fmaxf(fmaxf(sP[0][c], sP[1][c]), fmaxf(sP[2][c], sP[3][c]));
    float u = fmaxf(fmaxf(sR[0][c], sR[1][c]), fmaxf(sR[2][c], sR[3][c]));
    part_p[(size_t)blockIdx.x * 512 + c] = v;
    part_r[(size_t)blockIdx.x * 512 + c] = u;
  }
}

// colmax stage 2: reduce 1024 partial rows. part_r = part_p + 1024*512,
// m = [mp[512] | mr[512]]. grid 4 x 256.
__global__ __launch_bounds__(256) void colmax_red_k(const float* __restrict__ part,
                                                    float* __restrict__ m) {
  int idx = blockIdx.x * 256 + threadIdx.x;  // 0..1023
  int c = idx & 511;
  const float* P = part + (size_t)(idx >> 9) * (1024 * 512) + c;
  float v = -1e30f;
#pragma unroll 1
  for (int b = 0; b < 1024; b += 8) {
    float v0 = P[(size_t)(b + 0) * 512], v1 = P[(size_t)(b + 1) * 512];
    float v2 = P[(size_t)(b + 2) * 512], v3 = P[(size_t)(b + 3) * 512];
    float v4 = P[(size_t)(b + 4) * 512], v5 = P[(size_t)(b + 5) * 512];
    float v6 = P[(size_t)(b + 6) * 512], v7 = P[(size_t)(b + 7) * 512];
    float a = fmaxf(fmaxf(v0, v1), fmaxf(v2, v3));
    float bb = fmaxf(fmaxf(v4, v5), fmaxf(v6, v7));
    v = fmaxf(v, fmaxf(a, bb));
  }
  m[idx] = v;
}

// ---------------------------------------------------------------------------
// aggblend: per node n (one wave): z,z2 in regs over CSR in-edges; writes
// blend I-format in-place over Ea rows; tail writes z2I = split(z2/(z+eps)).
// Software-pipelined: next edge's 4 rows prefetched during current compute.
// ---------------------------------------------------------------------------
__global__ __launch_bounds__(256) void aggblend_k(float* __restrict__ EaB,
                                                  const float* __restrict__ Na,
                                                  const char* __restrict__ exI,
                                                  const char* __restrict__ nxI,
                                                  const int* __restrict__ src,
                                                  const int* __restrict__ off,
                                                  const int* __restrict__ eid,
                                                  const float* __restrict__ mp,
                                                  const float* __restrict__ mr,
                                                  char* __restrict__ z2I) {
  const int w = threadIdx.x >> 6, o = threadIdx.x & 63;
  int n = blockIdx.x * 4 + w;
  if (n >= NNODES) return;
  float m_p[8], m_r[8], nd[8], xd[8], z[8], z2[8];
#pragma unroll
  for (int j = 0; j < 8; j++) {
    m_p[j] = mp[o * 8 + j];
    m_r[j] = mr[o * 8 + j];
    z[j] = 0.f; z2[j] = 0.f;
  }
  {
    const float* np = Na + (size_t)n * 512 + o * 8;
    float4 d0 = *(const float4*)np, d1 = *(const float4*)(np + 4);
    nd[0] = d0.x; nd[1] = d0.y; nd[2] = d0.z; nd[3] = d0.w;
    nd[4] = d1.x; nd[5] = d1.y; nd[6] = d1.z; nd[7] = d1.w;
    const char* xb = nxI + (size_t)n * 2048 + o * 32;
    int ph = (n & 1) << 4;
    unsigned short hh[8], ll[8];
    unpack8(*(const uint4*)(xb + ph), hh);
    unpack8(*(const uint4*)(xb + (ph ^ 16)), ll);
#pragma unroll
    for (int j = 0; j < 8; j++) xd[j] = bf2f(hh[j]) + bf2f(ll[j]);
  }
  const int i0 = off[n], i1 = off[n + 1];
  if (i0 < i1) {
    int e = eid[i0];
    int s = src[e];
    const float* ea = EaB + (size_t)e * 512 + o * 8;
    float4 ca0 = *(const float4*)ea, ca1 = *(const float4*)(ea + 4);
    const float* ns = Na + (size_t)s * 512 + o * 8;
    float4 cs0 = *(const float4*)ns, cs1 = *(const float4*)(ns + 4);
    const char* xb = exI + (size_t)e * 2048 + o * 32;
    int phe = (e & 1) << 4;
    uint4 cx0 = *(const uint4*)(xb + phe), cx1 = *(const uint4*)(xb + (phe ^ 16));
    const char* sb = nxI + (size_t)s * 2048 + o * 32;
    int phs = (s & 1) << 4;
    uint4 cn0 = *(const uint4*)(sb + phs), cn1 = *(const uint4*)(sb + (phs ^ 16));
    for (int i = i0; i < i1; i++) {
      int en = 0, sn = 0;
      float4 pa0, pa1, ps0, ps1;
      uint4 px0, px1, pn0, pn1;
      const bool more = (i + 1 < i1);
      if (more) {
        en = eid[i + 1];
        sn = src[en];
        const float* ea2 = EaB + (size_t)en * 512 + o * 8;
        pa0 = *(const float4*)ea2; pa1 = *(const float4*)(ea2 + 4);
        const float* ns2 = Na + (size_t)sn * 512 + o * 8;
        ps0 = *(const float4*)ns2; ps1 = *(const float4*)(ns2 + 4);
        const char* xb2 = exI + (size_t)en * 2048 + o * 32;
        int ph2 = (en & 1) << 4;
        px0 = *(const uint4*)(xb2 + ph2); px1 = *(const uint4*)(xb2 + (ph2 ^ 16));
        const char* sb2 = nxI + (size_t)sn * 2048 + o * 32;
        int ph3 = (sn & 1) << 4;
        pn0 = *(const uint4*)(sb2 + ph3); pn1 = *(const uint4*)(sb2 + (ph3 ^ 16));
      }
      // compute current edge
      unsigned short xh[8], xl[8], sh[8], sl[8];
      unpack8(cx0, xh); unpack8(cx1, xl);
      unpack8(cn0, sh); unpack8(cn1, sl);
      float ev[8] = {ca0.x, ca0.y, ca0.z, ca0.w, ca1.x, ca1.y, ca1.z, ca1.w};
      float sv[8] = {cs0.x, cs0.y, cs0.z, cs0.w, cs1.x, cs1.y, cs1.z, cs1.w};
      unsigned short bh[8], bl2[8];
#pragma unroll
      for (int j = 0; j < 8; j++) {
        float sp = ev[j] + nd[j] - m_p[j];
        float sr = ev[j] + sv[j] - m_r[j];
        float ap = __expf(sp);
        float xe = bf2f(xh[j]) + bf2f(xl[j]);
        z[j] += ap;
        z2[j] += ap * xe;
        float u = sr - sp;
        float evx = __expf(-fabsf(u));
        float wpos = 1.f / (1.f + evx);
        float wr = (u >= 0.f) ? wpos : 1.f - wpos;
        float xs_ = bf2f(sh[j]) + bf2f(sl[j]);
        split2(wr * xs_ + (1.f - wr) * xd[j], bh[j], bl2[j]);
      }
      char* ob = (char*)EaB + (size_t)e * 2048 + o * 32;
      int phw = (e & 1) << 4;
      *(uint4*)(ob + phw) = pack8(bh);
      *(uint4*)(ob + (phw ^ 16)) = pack8(bl2);
      if (more) {
        e = en; s = sn;
        ca0 = pa0; ca1 = pa1; cs0 = ps0; cs1 = ps1;
        cx0 = px0; cx1 = px1; cn0 = pn0; cn1 = pn1;
      }
    }
  }
  unsigned short zh[8], zl[8];
#pragma unroll
  for (int j = 0; j < 8; j++) split2(z2[j] / (z[j] + EPS), zh[j], zl[j]);
  char* zb = z2I + (size_t)n * 2048 + o * 32;
  int phn = (n & 1) << 4;
  *(uint4*)(zb + phn) = pack8(zh);
  *(uint4*)(zb + (phn ^ 16)) = pack8(zl);
}

// node_conf = nx @ Wnc ([512,55])
__global__ __launch_bounds__(256) void nodeconf_k(const float* __restrict__ nx,
                                                  const float* __restrict__ Wnc,
                                                  float* __restrict__ out) {
  int w = threadIdx.x >> 6, lane = threadIdx.x & 63;
  int n = blockIdx.x * 4 + w;
  const float* r = nx + (size_t)n * D;
  if (lane < 55) {
    float acc = 0.f;
    for (int k = 0; k < D; k++) acc = fmaf(r[k], Wnc[k * 55 + lane], acc);
    out[(size_t)n * 55 + lane] = acc;
  }
}

// edge_conf = ex @ Wec ([512,2])
__global__ __launch_bounds__(256) void edgeconf_k(const float* __restrict__ ex,
                                                  const float* __restrict__ Wec,
                                                  float* __restrict__ out) {
  int w = threadIdx.x >> 6, lane = threadIdx.x & 63;
  int e = blockIdx.x * 4 + w;
  const float* r = ex + (size_t)e * D;
  float a0 = 0.f, a1 = 0.f;
#pragma unroll
  for (int j = 0; j < 8; j++) {
    int c = lane + j * 64;
    float x = r[c];
    a0 = fmaf(x, Wec[c * 2 + 0], a0);
    a1 = fmaf(x, Wec[c * 2 + 1], a1);
  }
#pragma unroll
  for (int off = 32; off; off >>= 1) {
    a0 += __shfl_down(a0, off);
    a1 += __shfl_down(a1, off);
  }
  if (lane == 0) { out[(size_t)e * 2 + 0] = a0; out[(size_t)e * 2 + 1] = a1; }
}

extern "C" void kernel_launch(void* const* d_in, const int* in_sizes, int n_in,
                              void* d_out, int out_size, void* d_ws, size_t ws_size,
                              hipStream_t stream) {
  const float* in_nx = (const float*)d_in[0];
  const float* in_ex = (const float*)d_in[1];
  const int* src = (const int*)d_in[2];
  const int* dst = (const int*)d_in[3];
  const float* Wa = (const float*)d_in[4];
  const float* Wn = (const float*)d_in[5];
  const float* We = (const float*)d_in[6];
  const float* Wnc = (const float*)d_in[7];
  const float* Wec = (const float*)d_in[8];

  float* out = (float*)d_out;
  float* o_nx = out;
  float* o_nc = o_nx + (size_t)NNODES * D;
  float* o_ex = o_nc + (size_t)NNODES * 55;
  float* o_ec = o_ex + (size_t)NEDGES * D;

  const size_t SZ_E = (size_t)NEDGES * 2048;   // 163.84 MB
  const size_t SZ_N = (size_t)NNODES * 2048;   // 20.48 MB
  const size_t MATSZ = (size_t)512 * 1024 * 4; // 2 MB
  char* w = (char*)d_ws;
  float* P1 = (float*)w;                        // Ea f32 -> blendI (in place)
  char* exA = w + SZ_E;                         // exI ping
  char* nxA = w + 2 * SZ_E;                     // nxI ping
  float* Na = (float*)(w + 2 * SZ_E + SZ_N);
  char* z2I = w + 2 * SZ_E + 2 * SZ_N;
  float* mpf = (float*)(w + 2 * SZ_E + 3 * SZ_N);  // [mp[512] | mr[512]]
  char* WT = w + 2 * SZ_E + 3 * SZ_N + 8192;
  char* csr = WT + 15 * MATSZ;
  int* cnt = (int*)csr;                          // NNODES
  int* offp = cnt + NNODES + 8;                  // NNODES+1
  int* cur = offp + NNODES + 8;
  int* eid = cur + NNODES + 8;                   // NEDGES
  float* part_p = (float*)(eid + NEDGES);        // 1024*512
  float* part_r = part_p + 1024 * 512;           // 1024*512

  char* exB = (char*)o_ex;   // 160 MB region, ping-pong
  char* nxB = (char*)o_nx;   // 20.48 MB region, ping-pong

  // one-time prep
  wprep_k<<<dim3(8, 16, 15), 256, 0, stream>>>(Wa, Wn, We, WT);
  splitI_k<<<2048, 256, 0, stream>>>(in_ex, exA, NEDGES * 64);
  splitI_k<<<2048, 256, 0, stream>>>(in_nx, nxA, NNODES * 64);
  hipMemsetAsync(cnt, 0, NNODES * sizeof(int), stream);
  hist_k<<<(NEDGES + 255) / 256, 256, 0, stream>>>(dst, cnt);
  scan_k<<<1, 256, 0, stream>>>(cnt, offp, cur);
  scatter_k<<<(NEDGES + 255) / 256, 256, 0, stream>>>(dst, cur, eid);

  dim3 gE(4, NEDGES / 128);           // (4, 625)
  dim3 gN(4, (NNODES + 127) / 128);   // (4, 79)

  for (int l = 0; l < LAYERS; l++) {
    const char* WaT = WT + (size_t)l * MATSZ;
    const char* WnT = WT + (size_t)(5 + l) * MATSZ;
    const char* WeT = WT + (size_t)(10 + l) * MATSZ;
    char* exCur = (l & 1) ? exB : exA;
    char* exNxt = (l & 1) ? exA : exB;
    char* nxCur = (l & 1) ? nxB : nxA;
    char* nxNxt = (l & 1) ? nxA : nxB;

    // Na = nx @ Wa_bot ; Ea = ex @ Wa_top
    gemmI<512, false, false><<<gN, 256, 0, stream>>>(nxCur, nullptr, WaT, 64, Na, NNODES);
    gemmI<512, false, false><<<gE, 256, 0, stream>>>(exCur, nullptr, WaT, 0, P1, NEDGES);

    colmax_part_k<<<1024, 256, 0, stream>>>(P1, Na, src, dst, part_p, part_r);
    colmax_red_k<<<4, 256, 0, stream>>>(part_p, mpf);

    aggblend_k<<<(NNODES + 3) / 4, 256, 0, stream>>>(P1, Na, exCur, nxCur, src,
                                                     offp, eid, mpf, mpf + 512, z2I);

    // node update: nx' = act(concat(z2, nx) @ Wn)
    if (l < 4)
      gemmI<1024, true, true><<<gN, 256, 0, stream>>>(z2I, nxCur, WnT, 0, nxNxt, NNODES);
    else
      gemmI<1024, true, false><<<gN, 256, 0, stream>>>(z2I, nxCur, WnT, 0, o_nx, NNODES);

    // edge update: ex' = act(concat(blend, ex) @ We)
    if (l < 4)
      gemmI<1024, true, true><<<gE, 256, 0, stream>>>((char*)P1, exCur, WeT, 0, exNxt, NEDGES);
    else
      gemmI<1024, true, false><<<gE, 256, 0, stream>>>((char*)P1, exCur, WeT, 0, o_ex, NEDGES);
  }

  nodeconf_k<<<NNODES / 4, 256, 0, stream>>>(o_nx, Wnc, o_nc);
  edgeconf_k<<<NEDGES / 4, 256, 0, stream>>>(o_ex, Wec, o_ec);
}

// Round 5
// 3167.074 us; speedup vs baseline: 4.5467x; 1.3805x over previous
//
#include <hip/hip_runtime.h>
#include <hip/hip_fp16.h>
#include <math.h>

#define D 512
#define NNODES 10000
#define NEDGES 80000
#define LAYERS 5
#define EPS 1e-5f

typedef _Float16 f16x8 __attribute__((ext_vector_type(8)));
typedef float f32x4 __attribute__((ext_vector_type(4)));

// ---------- fp16 helpers ----------
__device__ inline unsigned short f2h(float x) { return __half_as_ushort(__float2half(x)); }
__device__ inline float h2f(unsigned short u) { return __half2float(__ushort_as_half(u)); }
__device__ inline void splitW(float x, unsigned short& h, unsigned short& l) {
  h = f2h(x);
  l = f2h(x - h2f(h));
}
__device__ inline uint4 pack8(const unsigned short* v) {
  uint4 r;
  r.x = (unsigned)v[0] | ((unsigned)v[1] << 16);
  r.y = (unsigned)v[2] | ((unsigned)v[3] << 16);
  r.z = (unsigned)v[4] | ((unsigned)v[5] << 16);
  r.w = (unsigned)v[6] | ((unsigned)v[7] << 16);
  return r;
}
__device__ inline void unpack8(uint4 v, unsigned short* o) {
  o[0] = v.x & 0xffff; o[1] = v.x >> 16;
  o[2] = v.y & 0xffff; o[3] = v.y >> 16;
  o[4] = v.z & 0xffff; o[5] = v.z >> 16;
  o[6] = v.w & 0xffff; o[7] = v.w >> 16;
}

__device__ inline void gload16(const void* g, void* l) {
  __builtin_amdgcn_global_load_lds((const __attribute__((address_space(1))) void*)g,
                                   (__attribute__((address_space(3))) void*)l, 16, 0, 0);
}

// ---------------------------------------------------------------------------
// A-format (activations): fp16, row = 1024 B, 64 octets of 16 B. Within each
// 64 B K-block (4 octets), octet o sits at slot (o&3)^((r>>1)&3).
// W-format (weights): fp16 hi+lo, row = 4096 B, 128 octets of 32 B. Within
// each 128 B K-block, slot (o&3)^(r&3); hi 16B at parity ((r^(r>>2))&1).
// Both give conflict-free quarter-wave ds_read_b128 (8 classes x 2 lanes).
// ---------------------------------------------------------------------------
__device__ inline int octA(int r, int o) {
  return ((o >> 2) << 6) + ((((o & 3) ^ ((r >> 1) & 3))) << 4);
}
__device__ inline int octW(int r, int o) {
  return ((o >> 2) << 7) + (((o & 3) ^ (r & 3)) << 5) + ((((r >> 2) ^ r) & 1) << 4);
}

// f32 [R][512] -> A-format fp16
__global__ __launch_bounds__(256) void toF16_k(const float* __restrict__ src,
                                               char* __restrict__ dst, int nOct) {
  for (long long i = (long long)blockIdx.x * 256 + threadIdx.x; i < nOct;
       i += (long long)gridDim.x * 256) {
    int row = (int)(i >> 6), oct = (int)(i & 63);
    const float* s = src + (size_t)row * 512 + oct * 8;
    float4 x0 = *(const float4*)s, x1 = *(const float4*)(s + 4);
    float xs[8] = {x0.x, x0.y, x0.z, x0.w, x1.x, x1.y, x1.z, x1.w};
    unsigned short h[8];
#pragma unroll
    for (int j = 0; j < 8; j++) h[j] = f2h(xs[j]);
    *(uint4*)(dst + (size_t)row * 1024 + octA(row, oct)) = pack8(h);
  }
}

// weight prep: W[1024][512] f32 (15 mats) -> WT[n=512][k=1024] W-format
__global__ __launch_bounds__(256) void wprep_k(const float* __restrict__ Wa,
                                               const float* __restrict__ Wn,
                                               const float* __restrict__ We,
                                               char* __restrict__ WT) {
  __shared__ float tile[64][65];
  int mat = blockIdx.z;
  const float* W = (mat < 5) ? Wa + (size_t)mat * 1024 * 512
                 : (mat < 10) ? Wn + (size_t)(mat - 5) * 1024 * 512
                              : We + (size_t)(mat - 10) * 1024 * 512;
  char* out = WT + (size_t)mat * 512 * 4096;
  int n0 = blockIdx.x * 64, k0 = blockIdx.y * 64;
  int t = threadIdx.x;
  int ty = t >> 2, tx = t & 3;
  const float* wr = W + (size_t)(k0 + ty) * 512 + n0 + tx * 16;
  float4 v0 = *(const float4*)(wr + 0), v1 = *(const float4*)(wr + 4);
  float4 v2 = *(const float4*)(wr + 8), v3 = *(const float4*)(wr + 12);
  float vv[16] = {v0.x, v0.y, v0.z, v0.w, v1.x, v1.y, v1.z, v1.w,
                  v2.x, v2.y, v2.z, v2.w, v3.x, v3.y, v3.z, v3.w};
#pragma unroll
  for (int j = 0; j < 16; j++) tile[ty][tx * 16 + j] = vv[j];
  __syncthreads();
#pragma unroll
  for (int p = 0; p < 2; p++) {
    int chunk = t + p * 256;
    int n = chunk >> 3, cc = chunk & 7;
    float xs[8];
#pragma unroll
    for (int j = 0; j < 8; j++) xs[j] = tile[cc * 8 + j][n];
    unsigned short h[8], l[8];
#pragma unroll
    for (int j = 0; j < 8; j++) splitW(xs[j], h[j], l[j]);
    int ng = n0 + n;
    int kc = (k0 >> 3) + cc;
    char* bp = out + (size_t)ng * 4096;
    int ho = octW(ng, kc);
    *(uint4*)(bp + ho) = pack8(h);
    *(uint4*)(bp + (ho ^ 16)) = pack8(l);
  }
}

// ---------------------------------------------------------------------------
// CSR build over dst (dst fixed across layers)
// ---------------------------------------------------------------------------
__global__ __launch_bounds__(256) void hist_k(const int* __restrict__ dst, int* __restrict__ cnt) {
  int e = blockIdx.x * 256 + threadIdx.x;
  if (e < NEDGES) atomicAdd(&cnt[dst[e]], 1);
}

__global__ __launch_bounds__(256) void scan_k(const int* __restrict__ cnt,
                                              int* __restrict__ off, int* __restrict__ cur) {
  __shared__ int part[256];
  const int CH = (NNODES + 255) / 256;
  int t = threadIdx.x;
  int s = 0;
  int l0 = t * CH;
  for (int i = 0; i < CH; i++) {
    int idx = l0 + i;
    if (idx < NNODES) s += cnt[idx];
  }
  part[t] = s;
  __syncthreads();
  if (t == 0) {
    int acc = 0;
    for (int i = 0; i < 256; i++) { int v = part[i]; part[i] = acc; acc += v; }
  }
  __syncthreads();
  int acc = part[t];
  for (int i = 0; i < CH; i++) {
    int idx = l0 + i;
    if (idx < NNODES) { off[idx] = acc; cur[idx] = acc; acc += cnt[idx]; }
  }
  if (t == 255) off[NNODES] = acc;
}

__global__ __launch_bounds__(256) void scatter_k(const int* __restrict__ dst,
                                                 int* __restrict__ cur, int* __restrict__ eid) {
  int e = blockIdx.x * 256 + threadIdx.x;
  if (e < NEDGES) {
    int p = atomicAdd(&cur[dst[e]], 1);
    eid[p] = e;
  }
}

// ---------------------------------------------------------------------------
// GEMM: Y[R][512] = X@W, A fp16 single-term x W fp16 hi+lo (2 MFMA/pair).
// X rows A-format (byte strides s1/s2); W rows W-format (4096 B).
// ---------------------------------------------------------------------------
template<int KT, bool ACT, bool OUT_I>
__global__ __launch_bounds__(256) void gemmI(const char* __restrict__ X1, long s1,
                                             const char* __restrict__ X2, long s2,
                                             const char* __restrict__ BW, int cb0,
                                             void* __restrict__ Yout, int R) {
  __shared__ char smem[32768];
  char* As = smem;           // 8 KB: 128 rows x 64 B
  char* Bs = smem + 8192;    // 16 KB: 128 rows x 128 B
  const int tid = threadIdx.x;
  const int lane = tid & 63, wv = tid >> 6;
  // bijective XCD chunking: 4 col-blocks of one row-panel stay on one XCD
  int flat = blockIdx.y * 4 + blockIdx.x;
  int total = gridDim.y * 4;
  int xcd = flat & 7, idx = flat >> 3;
  int q = total >> 3, rem = total & 7;
  int base = xcd * q + (xcd < rem ? xcd : rem);
  int f2 = base + idx;
  const int bn0 = (f2 & 3) * 128, bm0 = (f2 >> 2) * 128;
  const int r16 = lane & 15, g = lane >> 4;
  const int mo = (wv >> 1) * 64, no = (wv & 1) * 64;
  const int lr8 = lane >> 3, ls8 = (lane & 7) * 16;
  const int lr16 = lane >> 2, ls16 = (lane & 3) * 16;
  f32x4 acc[4][4];
#pragma unroll
  for (int i = 0; i < 4; i++)
#pragma unroll
    for (int j = 0; j < 4; j++) acc[i][j] = (f32x4){0.f, 0.f, 0.f, 0.f};

  for (int kt = 0; kt < KT; kt += 32) {
    const char* ab;
    long sab;
    int acb;
    if (KT == 1024 && kt >= 512) { ab = X2; sab = s2; acb = (kt - 512) >> 3; }
    else { ab = X1; sab = s1; acb = kt >> 3; }
#pragma unroll
    for (int i = 0; i < 2; i++) {
      int rb = i * 4 + wv;                    // 0..7, 16 rows each
      int grow = bm0 + rb * 16 + lr16;
      if (grow > R - 1) grow = R - 1;
      gload16(ab + (size_t)grow * sab + acb * 16 + ls16, As + rb * 1024);
    }
    int bcb = cb0 + (kt >> 3);
#pragma unroll
    for (int i = 0; i < 4; i++) {
      int rb = i * 4 + wv;                    // 0..15, 8 rows each
      int nrow = bn0 + rb * 8 + lr8;
      gload16(BW + (size_t)nrow * 4096 + bcb * 32 + ls8, Bs + rb * 1024);
    }
    __syncthreads();
    f16x8 a[4], bh[4], bl[4];
#pragma unroll
    for (int mi = 0; mi < 4; mi++) {
      int row = mo + mi * 16 + r16;
      a[mi] = *(const f16x8*)(As + row * 64 + (((g ^ ((row >> 1) & 3))) << 4));
    }
#pragma unroll
    for (int ni = 0; ni < 4; ni++) {
      int row = no + ni * 16 + r16;
      int off = row * 128 + ((g ^ (row & 3)) << 5) + ((((row >> 2) ^ row) & 1) << 4);
      bh[ni] = *(const f16x8*)(Bs + off);
      bl[ni] = *(const f16x8*)(Bs + (off ^ 16));
    }
#pragma unroll
    for (int mi = 0; mi < 4; mi++)
#pragma unroll
      for (int ni = 0; ni < 4; ni++) {
        acc[mi][ni] = __builtin_amdgcn_mfma_f32_16x16x32_f16(a[mi], bh[ni], acc[mi][ni], 0, 0, 0);
        acc[mi][ni] = __builtin_amdgcn_mfma_f32_16x16x32_f16(a[mi], bl[ni], acc[mi][ni], 0, 0, 0);
      }
    __syncthreads();
  }

  if (!OUT_I) {
    float* Y = (float*)Yout;
#pragma unroll
    for (int mi = 0; mi < 4; mi++)
#pragma unroll
      for (int j = 0; j < 4; j++) {
        int row = bm0 + mo + mi * 16 + g * 4 + j;
        if (row < R) {
#pragma unroll
          for (int ni = 0; ni < 4; ni++) {
            float v = acc[mi][ni][j];
            if (ACT) v = (v >= 0.f) ? v : 0.01f * v;
            Y[(size_t)row * 512 + bn0 + no + ni * 16 + r16] = v;
          }
        }
      }
  } else {
    // LDS-staged A-format epilogue (stride 1024 B), two 64-row halves
    float* stg = (float*)smem;
#pragma unroll
    for (int h = 0; h < 2; h++) {
      __syncthreads();
      if ((wv >> 1) == h) {
#pragma unroll
        for (int mi = 0; mi < 4; mi++)
#pragma unroll
          for (int j = 0; j < 4; j++) {
            int rl = mi * 16 + g * 4 + j;
#pragma unroll
            for (int ni = 0; ni < 4; ni++) {
              float v = acc[mi][ni][j];
              if (ACT) v = (v >= 0.f) ? v : 0.01f * v;
              stg[rl * 128 + no + ni * 16 + r16] = v;
            }
          }
      }
      __syncthreads();
#pragma unroll
      for (int qq = 0; qq < 4; qq++) {
        int idx2 = tid + qq * 256;
        int rl = idx2 >> 4, oc = idx2 & 15;
        int grow = bm0 + h * 64 + rl;
        if (grow < R) {
          unsigned short hh[8];
#pragma unroll
          for (int j = 0; j < 8; j++) hh[j] = f2h(stg[rl * 128 + oc * 8 + j]);
          int oct = (bn0 >> 3) + oc;
          *(uint4*)((char*)Yout + (size_t)grow * 1024 + octA(grow, oct)) = pack8(hh);
        }
      }
    }
  }
}

// ---------------------------------------------------------------------------
// colmax stage 1: per-block partial column maxes, no atomics.
// ---------------------------------------------------------------------------
__global__ __launch_bounds__(256) void colmax_part_k(const float* __restrict__ Ea,
                                                     const float* __restrict__ Na,
                                                     const int* __restrict__ src,
                                                     const int* __restrict__ dst,
                                                     float* __restrict__ part_p,
                                                     float* __restrict__ part_r) {
  __shared__ float sP[4][512];
  __shared__ float sR[4][512];
  const int g = threadIdx.x >> 6, o = threadIdx.x & 63;
  float pm[8], rm[8];
#pragma unroll
  for (int j = 0; j < 8; j++) { pm[j] = -1e30f; rm[j] = -1e30f; }
  for (int e = blockIdx.x * 8 + g * 2; e < NEDGES; e += 8192) {
    int dA = dst[e], sA = src[e], dB = dst[e + 1], sB = src[e + 1];
    const float* eaA = Ea + (size_t)e * 512 + o * 8;
    const float* eaB = Ea + (size_t)(e + 1) * 512 + o * 8;
    float4 aA0 = *(const float4*)eaA, aA1 = *(const float4*)(eaA + 4);
    float4 aB0 = *(const float4*)eaB, aB1 = *(const float4*)(eaB + 4);
    const float* ndA = Na + (size_t)dA * 512 + o * 8;
    const float* nsA = Na + (size_t)sA * 512 + o * 8;
    const float* ndB = Na + (size_t)dB * 512 + o * 8;
    const float* nsB = Na + (size_t)sB * 512 + o * 8;
    float4 dA0 = *(const float4*)ndA, dA1 = *(const float4*)(ndA + 4);
    float4 sA0 = *(const float4*)nsA, sA1 = *(const float4*)(nsA + 4);
    float4 dB0 = *(const float4*)ndB, dB1 = *(const float4*)(ndB + 4);
    float4 sB0 = *(const float4*)nsB, sB1 = *(const float4*)(nsB + 4);
    float eA[8] = {aA0.x, aA0.y, aA0.z, aA0.w, aA1.x, aA1.y, aA1.z, aA1.w};
    float eB[8] = {aB0.x, aB0.y, aB0.z, aB0.w, aB1.x, aB1.y, aB1.z, aB1.w};
    float dvA[8] = {dA0.x, dA0.y, dA0.z, dA0.w, dA1.x, dA1.y, dA1.z, dA1.w};
    float svA[8] = {sA0.x, sA0.y, sA0.z, sA0.w, sA1.x, sA1.y, sA1.z, sA1.w};
    float dvB[8] = {dB0.x, dB0.y, dB0.z, dB0.w, dB1.x, dB1.y, dB1.z, dB1.w};
    float svB[8] = {sB0.x, sB0.y, sB0.z, sB0.w, sB1.x, sB1.y, sB1.z, sB1.w};
#pragma unroll
    for (int j = 0; j < 8; j++) {
      pm[j] = fmaxf(pm[j], fmaxf(eA[j] + dvA[j], eB[j] + dvB[j]));
      rm[j] = fmaxf(rm[j], fmaxf(eA[j] + svA[j], eB[j] + svB[j]));
    }
  }
#pragma unroll
  for (int j = 0; j < 8; j++) { sP[g][o * 8 + j] = pm[j]; sR[g][o * 8 + j] = rm[j]; }
  __syncthreads();
  for (int c = threadIdx.x; c < 512; c += 256) {
    float v = fmaxf(fmaxf(sP[0][c], sP[1][c]), fmaxf(sP[2][c], sP[3][c]));
    float u = fmaxf(fmaxf(sR[0][c], sR[1][c]), fmaxf(sR[2][c], sR[3][c]));
    part_p[(size_t)blockIdx.x * 512 + c] = v;
    part_r[(size_t)blockIdx.x * 512 + c] = u;
  }
}

__global__ __launch_bounds__(256) void colmax_red_k(const float* __restrict__ part,
                                                    float* __restrict__ m) {
  int idx = blockIdx.x * 256 + threadIdx.x;  // 0..1023
  int c = idx & 511;
  const float* P = part + (size_t)(idx >> 9) * (1024 * 512) + c;
  float v = -1e30f;
#pragma unroll 1
  for (int b = 0; b < 1024; b += 8) {
    float v0 = P[(size_t)(b + 0) * 512], v1 = P[(size_t)(b + 1) * 512];
    float v2 = P[(size_t)(b + 2) * 512], v3 = P[(size_t)(b + 3) * 512];
    float v4 = P[(size_t)(b + 4) * 512], v5 = P[(size_t)(b + 5) * 512];
    float v6 = P[(size_t)(b + 6) * 512], v7 = P[(size_t)(b + 7) * 512];
    float a = fmaxf(fmaxf(v0, v1), fmaxf(v2, v3));
    float bb = fmaxf(fmaxf(v4, v5), fmaxf(v6, v7));
    v = fmaxf(v, fmaxf(a, bb));
  }
  m[idx] = v;
}

// ---------------------------------------------------------------------------
// aggblend: per node n (one wave): z,z2 in regs over CSR in-edges; writes
// blend A-format (stride 2048) in-place over Ea; tail writes z2I.
// ---------------------------------------------------------------------------
__global__ __launch_bounds__(256) void aggblend_k(float* __restrict__ EaB,
                                                  const float* __restrict__ Na,
                                                  const char* __restrict__ exI,
                                                  const char* __restrict__ nxI,
                                                  const int* __restrict__ src,
                                                  const int* __restrict__ off,
                                                  const int* __restrict__ eid,
                                                  const float* __restrict__ mp,
                                                  const float* __restrict__ mr,
                                                  char* __restrict__ z2I) {
  const int w = threadIdx.x >> 6, o = threadIdx.x & 63;
  int n = blockIdx.x * 4 + w;
  if (n >= NNODES) return;
  float m_p[8], m_r[8], nd[8], xd[8], z[8], z2[8];
#pragma unroll
  for (int j = 0; j < 8; j++) {
    m_p[j] = mp[o * 8 + j];
    m_r[j] = mr[o * 8 + j];
    z[j] = 0.f; z2[j] = 0.f;
  }
  {
    const float* np = Na + (size_t)n * 512 + o * 8;
    float4 d0 = *(const float4*)np, d1 = *(const float4*)(np + 4);
    nd[0] = d0.x; nd[1] = d0.y; nd[2] = d0.z; nd[3] = d0.w;
    nd[4] = d1.x; nd[5] = d1.y; nd[6] = d1.z; nd[7] = d1.w;
    unsigned short hh[8];
    unpack8(*(const uint4*)(nxI + (size_t)n * 1024 + octA(n, o)), hh);
#pragma unroll
    for (int j = 0; j < 8; j++) xd[j] = h2f(hh[j]);
  }
  const int i0 = off[n], i1 = off[n + 1];
  if (i0 < i1) {
    int e = eid[i0];
    int s = src[e];
    const float* ea = EaB + (size_t)e * 512 + o * 8;
    float4 ca0 = *(const float4*)ea, ca1 = *(const float4*)(ea + 4);
    const float* ns = Na + (size_t)s * 512 + o * 8;
    float4 cs0 = *(const float4*)ns, cs1 = *(const float4*)(ns + 4);
    uint4 cx = *(const uint4*)(exI + (size_t)e * 1024 + octA(e, o));
    uint4 cn = *(const uint4*)(nxI + (size_t)s * 1024 + octA(s, o));
    for (int i = i0; i < i1; i++) {
      int en = 0, sn = 0;
      float4 pa0, pa1, ps0, ps1;
      uint4 px, pn;
      const bool more = (i + 1 < i1);
      if (more) {
        en = eid[i + 1];
        sn = src[en];
        const float* ea2 = EaB + (size_t)en * 512 + o * 8;
        pa0 = *(const float4*)ea2; pa1 = *(const float4*)(ea2 + 4);
        const float* ns2 = Na + (size_t)sn * 512 + o * 8;
        ps0 = *(const float4*)ns2; ps1 = *(const float4*)(ns2 + 4);
        px = *(const uint4*)(exI + (size_t)en * 1024 + octA(en, o));
        pn = *(const uint4*)(nxI + (size_t)sn * 1024 + octA(sn, o));
      }
      unsigned short xh[8], sh[8];
      unpack8(cx, xh);
      unpack8(cn, sh);
      float ev[8] = {ca0.x, ca0.y, ca0.z, ca0.w, ca1.x, ca1.y, ca1.z, ca1.w};
      float sv[8] = {cs0.x, cs0.y, cs0.z, cs0.w, cs1.x, cs1.y, cs1.z, cs1.w};
      unsigned short bh[8];
#pragma unroll
      for (int j = 0; j < 8; j++) {
        float sp = ev[j] + nd[j] - m_p[j];
        float sr = ev[j] + sv[j] - m_r[j];
        float ap = __expf(sp);
        float xe = h2f(xh[j]);
        z[j] += ap;
        z2[j] += ap * xe;
        float u = sr - sp;
        float evx = __expf(-fabsf(u));
        float wpos = 1.f / (1.f + evx);
        float wr = (u >= 0.f) ? wpos : 1.f - wpos;
        float xs_ = h2f(sh[j]);
        bh[j] = f2h(wr * xs_ + (1.f - wr) * xd[j]);
      }
      *(uint4*)((char*)EaB + (size_t)e * 2048 + octA(e, o)) = pack8(bh);
      if (more) {
        e = en; s = sn;
        ca0 = pa0; ca1 = pa1; cs0 = ps0; cs1 = ps1;
        cx = px; cn = pn;
      }
    }
  }
  unsigned short zh[8];
#pragma unroll
  for (int j = 0; j < 8; j++) zh[j] = f2h(z2[j] / (z[j] + EPS));
  *(uint4*)(z2I + (size_t)n * 1024 + octA(n, o)) = pack8(zh);
}

// node_conf = nx @ Wnc ([512,55])
__global__ __launch_bounds__(256) void nodeconf_k(const float* __restrict__ nx,
                                                  const float* __restrict__ Wnc,
                                                  float* __restrict__ out) {
  int w = threadIdx.x >> 6, lane = threadIdx.x & 63;
  int n = blockIdx.x * 4 + w;
  const float* r = nx + (size_t)n * D;
  if (lane < 55) {
    float acc = 0.f;
    for (int k = 0; k < D; k++) acc = fmaf(r[k], Wnc[k * 55 + lane], acc);
    out[(size_t)n * 55 + lane] = acc;
  }
}

// edge_conf = ex @ Wec ([512,2])
__global__ __launch_bounds__(256) void edgeconf_k(const float* __restrict__ ex,
                                                  const float* __restrict__ Wec,
                                                  float* __restrict__ out) {
  int w = threadIdx.x >> 6, lane = threadIdx.x & 63;
  int e = blockIdx.x * 4 + w;
  const float* r = ex + (size_t)e * D;
  float a0 = 0.f, a1 = 0.f;
#pragma unroll
  for (int j = 0; j < 8; j++) {
    int c = lane + j * 64;
    float x = r[c];
    a0 = fmaf(x, Wec[c * 2 + 0], a0);
    a1 = fmaf(x, Wec[c * 2 + 1], a1);
  }
#pragma unroll
  for (int off = 32; off; off >>= 1) {
    a0 += __shfl_down(a0, off);
    a1 += __shfl_down(a1, off);
  }
  if (lane == 0) { out[(size_t)e * 2 + 0] = a0; out[(size_t)e * 2 + 1] = a1; }
}

extern "C" void kernel_launch(void* const* d_in, const int* in_sizes, int n_in,
                              void* d_out, int out_size, void* d_ws, size_t ws_size,
                              hipStream_t stream) {
  const float* in_nx = (const float*)d_in[0];
  const float* in_ex = (const float*)d_in[1];
  const int* src = (const int*)d_in[2];
  const int* dst = (const int*)d_in[3];
  const float* Wa = (const float*)d_in[4];
  const float* Wn = (const float*)d_in[5];
  const float* We = (const float*)d_in[6];
  const float* Wnc = (const float*)d_in[7];
  const float* Wec = (const float*)d_in[8];

  float* out = (float*)d_out;
  float* o_nx = out;
  float* o_nc = o_nx + (size_t)NNODES * D;
  float* o_ex = o_nc + (size_t)NNODES * 55;
  float* o_ec = o_ex + (size_t)NEDGES * D;

  const size_t SZ_EA = (size_t)NEDGES * 2048;   // Ea f32 / blend region
  const size_t SZ_EH = (size_t)NEDGES * 1024;   // edge fp16 rows
  const size_t SZ_NH = (size_t)NNODES * 1024;   // node fp16 rows
  const size_t SZ_NF = (size_t)NNODES * 2048;   // node f32 rows
  const size_t MATSZ = (size_t)512 * 4096;      // 2 MB per weight mat
  char* w = (char*)d_ws;
  float* P1 = (float*)w;                        // Ea f32 -> blend fp16 (stride 2048)
  char* exA = w + SZ_EA;                        // exI ping (fp16)
  char* nxA = w + SZ_EA + SZ_EH;                // nxI ping (fp16)
  float* Na = (float*)(w + SZ_EA + SZ_EH + SZ_NH);
  char* z2I = w + SZ_EA + SZ_EH + SZ_NH + SZ_NF;
  float* mpf = (float*)(w + SZ_EA + SZ_EH + 2 * SZ_NH + SZ_NF);  // [mp|mr]
  char* WT = w + SZ_EA + SZ_EH + 2 * SZ_NH + SZ_NF + 8192;
  char* csr = WT + 15 * MATSZ;
  int* cnt = (int*)csr;
  int* offp = cnt + NNODES + 8;
  int* cur = offp + NNODES + 8;
  int* eid = cur + NNODES + 8;
  float* part_p = (float*)(eid + NEDGES);       // 1024*512
  float* part_r = part_p + 1024 * 512;

  char* exB = (char*)o_ex;   // fp16 ping in 160MB f32 region
  char* nxB = (char*)o_nx;

  // one-time prep
  wprep_k<<<dim3(8, 16, 15), 256, 0, stream>>>(Wa, Wn, We, WT);
  toF16_k<<<2048, 256, 0, stream>>>(in_ex, exA, NEDGES * 64);
  toF16_k<<<2048, 256, 0, stream>>>(in_nx, nxA, NNODES * 64);
  hipMemsetAsync(cnt, 0, NNODES * sizeof(int), stream);
  hist_k<<<(NEDGES + 255) / 256, 256, 0, stream>>>(dst, cnt);
  scan_k<<<1, 256, 0, stream>>>(cnt, offp, cur);
  scatter_k<<<(NEDGES + 255) / 256, 256, 0, stream>>>(dst, cur, eid);

  dim3 gE(4, NEDGES / 128);           // (4, 625)
  dim3 gN(4, (NNODES + 127) / 128);   // (4, 79)

  for (int l = 0; l < LAYERS; l++) {
    const char* WaT = WT + (size_t)l * MATSZ;
    const char* WnT = WT + (size_t)(5 + l) * MATSZ;
    const char* WeT = WT + (size_t)(10 + l) * MATSZ;
    char* exCur = (l & 1) ? exB : exA;
    char* exNxt = (l & 1) ? exA : exB;
    char* nxCur = (l & 1) ? nxB : nxA;
    char* nxNxt = (l & 1) ? nxA : nxB;

    // Na = nx @ Wa_bot ; Ea = ex @ Wa_top
    gemmI<512, false, false><<<gN, 256, 0, stream>>>(nxCur, 1024, nullptr, 0, WaT, 64, Na, NNODES);
    gemmI<512, false, false><<<gE, 256, 0, stream>>>(exCur, 1024, nullptr, 0, WaT, 0, P1, NEDGES);

    colmax_part_k<<<1024, 256, 0, stream>>>(P1, Na, src, dst, part_p, part_r);
    colmax_red_k<<<4, 256, 0, stream>>>(part_p, mpf);

    aggblend_k<<<(NNODES + 3) / 4, 256, 0, stream>>>(P1, Na, exCur, nxCur, src,
                                                     offp, eid, mpf, mpf + 512, z2I);

    // node update: nx' = act(concat(z2, nx) @ Wn)
    if (l < 4)
      gemmI<1024, true, true><<<gN, 256, 0, stream>>>(z2I, 1024, nxCur, 1024, WnT, 0, nxNxt, NNODES);
    else
      gemmI<1024, true, false><<<gN, 256, 0, stream>>>(z2I, 1024, nxCur, 1024, WnT, 0, o_nx, NNODES);

    // edge update: ex' = act(concat(blend, ex) @ We); blend stride 2048
    if (l < 4)
      gemmI<1024, true, true><<<gE, 256, 0, stream>>>((char*)P1, 2048, exCur, 1024, WeT, 0, exNxt, NEDGES);
    else
      gemmI<1024, true, false><<<gE, 256, 0, stream>>>((char*)P1, 2048, exCur, 1024, WeT, 0, o_ex, NEDGES);
  }

  nodeconf_k<<<NNODES / 4, 256, 0, stream>>>(o_nx, Wnc, o_nc);
  edgeconf_k<<<NEDGES / 4, 256, 0, stream>>>(o_ex, Wec, o_ec);
}

// Round 6
// 2760.559 us; speedup vs baseline: 5.2162x; 1.1473x over previous
//
#include <hip/hip_runtime.h>
#include <hip/hip_fp16.h>
#include <math.h>

#define D 512
#define NNODES 10000
#define NEDGES 80000
#define LAYERS 5
#define EPS 1e-5f

typedef _Float16 f16x8 __attribute__((ext_vector_type(8)));
typedef float f32x4 __attribute__((ext_vector_type(4)));

// ---------- fp16 helpers ----------
__device__ inline unsigned short f2h(float x) { return __half_as_ushort(__float2half(x)); }
__device__ inline float h2f(unsigned short u) { return __half2float(__ushort_as_half(u)); }
__device__ inline void splitW(float x, unsigned short& h, unsigned short& l) {
  h = f2h(x);
  l = f2h(x - h2f(h));
}
__device__ inline uint4 pack8(const unsigned short* v) {
  uint4 r;
  r.x = (unsigned)v[0] | ((unsigned)v[1] << 16);
  r.y = (unsigned)v[2] | ((unsigned)v[3] << 16);
  r.z = (unsigned)v[4] | ((unsigned)v[5] << 16);
  r.w = (unsigned)v[6] | ((unsigned)v[7] << 16);
  return r;
}
__device__ inline void unpack8(uint4 v, unsigned short* o) {
  o[0] = v.x & 0xffff; o[1] = v.x >> 16;
  o[2] = v.y & 0xffff; o[3] = v.y >> 16;
  o[4] = v.z & 0xffff; o[5] = v.z >> 16;
  o[6] = v.w & 0xffff; o[7] = v.w >> 16;
}

__device__ inline void gload16(const void* g, void* l) {
  __builtin_amdgcn_global_load_lds((const __attribute__((address_space(1))) void*)g,
                                   (__attribute__((address_space(3))) void*)l, 16, 0, 0);
}

// ---------------------------------------------------------------------------
// A-format (activations): fp16, row = 1024 B, 64 octets of 16 B. Within each
// 64 B K-block (4 octets), octet o sits at slot (o&3)^((r>>1)&3).
// W-format (weights): fp16 hi+lo, row = 4096 B; within each 128 B K-block,
// slot (o&3)^(r&3); hi 16B at parity ((r^(r>>2))&1).
// ---------------------------------------------------------------------------
__device__ inline int octA(int r, int o) {
  return ((o >> 2) << 6) + ((((o & 3) ^ ((r >> 1) & 3))) << 4);
}
__device__ inline int octW(int r, int o) {
  return ((o >> 2) << 7) + (((o & 3) ^ (r & 3)) << 5) + ((((r >> 2) ^ r) & 1) << 4);
}

// f32 [R][512] -> A-format fp16
__global__ __launch_bounds__(256) void toF16_k(const float* __restrict__ src,
                                               char* __restrict__ dst, int nOct) {
  for (long long i = (long long)blockIdx.x * 256 + threadIdx.x; i < nOct;
       i += (long long)gridDim.x * 256) {
    int row = (int)(i >> 6), oct = (int)(i & 63);
    const float* s = src + (size_t)row * 512 + oct * 8;
    float4 x0 = *(const float4*)s, x1 = *(const float4*)(s + 4);
    float xs[8] = {x0.x, x0.y, x0.z, x0.w, x1.x, x1.y, x1.z, x1.w};
    unsigned short h[8];
#pragma unroll
    for (int j = 0; j < 8; j++) h[j] = f2h(xs[j]);
    *(uint4*)(dst + (size_t)row * 1024 + octA(row, oct)) = pack8(h);
  }
}

// weight prep: W[1024][512] f32 (15 mats) -> WT[n=512][k=1024] W-format
__global__ __launch_bounds__(256) void wprep_k(const float* __restrict__ Wa,
                                               const float* __restrict__ Wn,
                                               const float* __restrict__ We,
                                               char* __restrict__ WT) {
  __shared__ float tile[64][65];
  int mat = blockIdx.z;
  const float* W = (mat < 5) ? Wa + (size_t)mat * 1024 * 512
                 : (mat < 10) ? Wn + (size_t)(mat - 5) * 1024 * 512
                              : We + (size_t)(mat - 10) * 1024 * 512;
  char* out = WT + (size_t)mat * 512 * 4096;
  int n0 = blockIdx.x * 64, k0 = blockIdx.y * 64;
  int t = threadIdx.x;
  int ty = t >> 2, tx = t & 3;
  const float* wr = W + (size_t)(k0 + ty) * 512 + n0 + tx * 16;
  float4 v0 = *(const float4*)(wr + 0), v1 = *(const float4*)(wr + 4);
  float4 v2 = *(const float4*)(wr + 8), v3 = *(const float4*)(wr + 12);
  float vv[16] = {v0.x, v0.y, v0.z, v0.w, v1.x, v1.y, v1.z, v1.w,
                  v2.x, v2.y, v2.z, v2.w, v3.x, v3.y, v3.z, v3.w};
#pragma unroll
  for (int j = 0; j < 16; j++) tile[ty][tx * 16 + j] = vv[j];
  __syncthreads();
#pragma unroll
  for (int p = 0; p < 2; p++) {
    int chunk = t + p * 256;
    int n = chunk >> 3, cc = chunk & 7;
    float xs[8];
#pragma unroll
    for (int j = 0; j < 8; j++) xs[j] = tile[cc * 8 + j][n];
    unsigned short h[8], l[8];
#pragma unroll
    for (int j = 0; j < 8; j++) splitW(xs[j], h[j], l[j]);
    int ng = n0 + n;
    int kc = (k0 >> 3) + cc;
    char* bp = out + (size_t)ng * 4096;
    int ho = octW(ng, kc);
    *(uint4*)(bp + ho) = pack8(h);
    *(uint4*)(bp + (ho ^ 16)) = pack8(l);
  }
}

// ---------------------------------------------------------------------------
// CSR build over dst (dst fixed across layers)
// ---------------------------------------------------------------------------
__global__ __launch_bounds__(256) void hist_k(const int* __restrict__ dst, int* __restrict__ cnt) {
  int e = blockIdx.x * 256 + threadIdx.x;
  if (e < NEDGES) atomicAdd(&cnt[dst[e]], 1);
}

__global__ __launch_bounds__(256) void scan_k(const int* __restrict__ cnt,
                                              int* __restrict__ off, int* __restrict__ cur) {
  __shared__ int part[256];
  const int CH = (NNODES + 255) / 256;
  int t = threadIdx.x;
  int s = 0;
  int l0 = t * CH;
  for (int i = 0; i < CH; i++) {
    int idx = l0 + i;
    if (idx < NNODES) s += cnt[idx];
  }
  part[t] = s;
  __syncthreads();
  if (t == 0) {
    int acc = 0;
    for (int i = 0; i < 256; i++) { int v = part[i]; part[i] = acc; acc += v; }
  }
  __syncthreads();
  int acc = part[t];
  for (int i = 0; i < CH; i++) {
    int idx = l0 + i;
    if (idx < NNODES) { off[idx] = acc; cur[idx] = acc; acc += cnt[idx]; }
  }
  if (t == 255) off[NNODES] = acc;
}

__global__ __launch_bounds__(256) void scatter_k(const int* __restrict__ dst,
                                                 int* __restrict__ cur, int* __restrict__ eid) {
  int e = blockIdx.x * 256 + threadIdx.x;
  if (e < NEDGES) {
    int p = atomicAdd(&cur[dst[e]], 1);
    eid[p] = e;
  }
}

// ---------------------------------------------------------------------------
// GEMM: Y[R][512] = X@W, A fp16 x W fp16 hi+lo (2 MFMA/pair).
// CMAX: fused per-panel column-max partials of (Y_fp16 + Na[dst]) / (+Na[src]).
// ---------------------------------------------------------------------------
template<int KT, bool ACT, bool OUT_I, bool CMAX>
__global__ __launch_bounds__(256) void gemmI(const char* __restrict__ X1, long s1,
                                             const char* __restrict__ X2, long s2,
                                             const char* __restrict__ BW, int cb0,
                                             void* __restrict__ Yout, int R,
                                             const int* __restrict__ srcI,
                                             const int* __restrict__ dstI,
                                             const float* __restrict__ Na,
                                             float* __restrict__ part_p,
                                             float* __restrict__ part_r) {
  __shared__ char smem[32768];
  char* As = smem;           // 8 KB: 128 rows x 64 B
  char* Bs = smem + 8192;    // 16 KB: 128 rows x 128 B
  const int tid = threadIdx.x;
  const int lane = tid & 63, wv = tid >> 6;
  // bijective XCD chunking
  int flat = blockIdx.y * 4 + blockIdx.x;
  int total = gridDim.y * 4;
  int xcd = flat & 7, idx = flat >> 3;
  int q = total >> 3, rem = total & 7;
  int base = xcd * q + (xcd < rem ? xcd : rem);
  int f2 = base + idx;
  const int bn0 = (f2 & 3) * 128, bm0 = (f2 >> 2) * 128;
  const int r16 = lane & 15, g = lane >> 4;
  const int mo = (wv >> 1) * 64, no = (wv & 1) * 64;
  const int lr8 = lane >> 3, ls8 = (lane & 7) * 16;
  const int lr16 = lane >> 2, ls16 = (lane & 3) * 16;
  f32x4 acc[4][4];
#pragma unroll
  for (int i = 0; i < 4; i++)
#pragma unroll
    for (int j = 0; j < 4; j++) acc[i][j] = (f32x4){0.f, 0.f, 0.f, 0.f};

  // loop-invariant LDS fragment offsets
  int offA[4], offB[4];
#pragma unroll
  for (int mi = 0; mi < 4; mi++) {
    int row = mo + mi * 16 + r16;
    offA[mi] = row * 64 + ((g ^ ((row >> 1) & 3)) << 4);
  }
#pragma unroll
  for (int ni = 0; ni < 4; ni++) {
    int row = no + ni * 16 + r16;
    offB[ni] = row * 128 + ((g ^ (row & 3)) << 5) + ((((row >> 2) ^ row) & 1) << 4);
  }

  // incrementing global pointers
  const char* pA0;
  const char* pA1;
  {
    int g0 = bm0 + wv * 16 + lr16; if (g0 > R - 1) g0 = R - 1;
    int g1 = bm0 + (4 + wv) * 16 + lr16; if (g1 > R - 1) g1 = R - 1;
    pA0 = X1 + (size_t)g0 * s1 + ls16;
    pA1 = X1 + (size_t)g1 * s1 + ls16;
  }
  const char* pB[4];
#pragma unroll
  for (int i = 0; i < 4; i++) {
    int nrow = bn0 + (i * 4 + wv) * 8 + lr8;
    pB[i] = BW + (size_t)nrow * 4096 + cb0 * 32 + ls8;
  }

  for (int kt = 0; kt < KT; kt += 32) {
    if (KT == 1024 && kt == 512) {
      int g0 = bm0 + wv * 16 + lr16; if (g0 > R - 1) g0 = R - 1;
      int g1 = bm0 + (4 + wv) * 16 + lr16; if (g1 > R - 1) g1 = R - 1;
      pA0 = X2 + (size_t)g0 * s2 + ls16;
      pA1 = X2 + (size_t)g1 * s2 + ls16;
    }
    gload16(pA0, As + wv * 1024);
    gload16(pA1, As + (4 + wv) * 1024);
#pragma unroll
    for (int i = 0; i < 4; i++) gload16(pB[i], Bs + (i * 4 + wv) * 1024);
    __syncthreads();
    f16x8 a[4], bhv[4], blv[4];
#pragma unroll
    for (int mi = 0; mi < 4; mi++) a[mi] = *(const f16x8*)(As + offA[mi]);
#pragma unroll
    for (int ni = 0; ni < 4; ni++) {
      bhv[ni] = *(const f16x8*)(Bs + offB[ni]);
      blv[ni] = *(const f16x8*)(Bs + (offB[ni] ^ 16));
    }
#pragma unroll
    for (int mi = 0; mi < 4; mi++)
#pragma unroll
      for (int ni = 0; ni < 4; ni++) {
        acc[mi][ni] = __builtin_amdgcn_mfma_f32_16x16x32_f16(a[mi], bhv[ni], acc[mi][ni], 0, 0, 0);
        acc[mi][ni] = __builtin_amdgcn_mfma_f32_16x16x32_f16(a[mi], blv[ni], acc[mi][ni], 0, 0, 0);
      }
    __syncthreads();
    pA0 += 64; pA1 += 64;
#pragma unroll
    for (int i = 0; i < 4; i++) pB[i] += 128;
  }

  if (!OUT_I) {
    float* Y = (float*)Yout;
#pragma unroll
    for (int mi = 0; mi < 4; mi++)
#pragma unroll
      for (int j = 0; j < 4; j++) {
        int row = bm0 + mo + mi * 16 + g * 4 + j;
        if (row < R) {
#pragma unroll
          for (int ni = 0; ni < 4; ni++) {
            float v = acc[mi][ni][j];
            if (ACT) v = (v >= 0.f) ? v : 0.01f * v;
            Y[(size_t)row * 512 + bn0 + no + ni * 16 + r16] = v;
          }
        }
      }
  } else {
    // LDS-staged A-format epilogue, two 64-row halves; optional fused colmax
    float* stg = (float*)smem;
    float mpv = -1e30f, mrv = -1e30f;
    const int cc = tid & 127, rh = tid >> 7;
#pragma unroll
    for (int h = 0; h < 2; h++) {
      __syncthreads();
      if ((wv >> 1) == h) {
#pragma unroll
        for (int mi = 0; mi < 4; mi++)
#pragma unroll
          for (int j = 0; j < 4; j++) {
            int rl = mi * 16 + g * 4 + j;
#pragma unroll
            for (int ni = 0; ni < 4; ni++) {
              float v = acc[mi][ni][j];
              if (ACT) v = (v >= 0.f) ? v : 0.01f * v;
              stg[rl * 128 + no + ni * 16 + r16] = v;
            }
          }
      }
      __syncthreads();
#pragma unroll
      for (int qq = 0; qq < 4; qq++) {
        int idx2 = tid + qq * 256;
        int rl = idx2 >> 4, oc = idx2 & 15;
        int grow = bm0 + h * 64 + rl;
        if (grow < R) {
          unsigned short hh[8];
#pragma unroll
          for (int j = 0; j < 8; j++) hh[j] = f2h(stg[rl * 128 + oc * 8 + j]);
          int oct = (bn0 >> 3) + oc;
          *(uint4*)((char*)Yout + (size_t)grow * 1024 + octA(grow, oct)) = pack8(hh);
        }
      }
      if (CMAX) {
        for (int r = rh * 32; r < rh * 32 + 32; r++) {
          int grow = bm0 + h * 64 + r;
          int d = dstI[grow], s = srcI[grow];
          float v = h2f(f2h(stg[r * 128 + cc]));
          mpv = fmaxf(mpv, v + Na[(size_t)d * 512 + bn0 + cc]);
          mrv = fmaxf(mrv, v + Na[(size_t)s * 512 + bn0 + cc]);
        }
      }
    }
    if (CMAX) {
      __syncthreads();
      float* red = (float*)smem;
      red[rh * 128 + cc] = mpv;
      red[256 + rh * 128 + cc] = mrv;
      __syncthreads();
      if (tid < 128) {
        int panel = f2 >> 2;
        part_p[(size_t)panel * 512 + bn0 + cc] = fmaxf(red[cc], red[128 + cc]);
        part_r[(size_t)panel * 512 + bn0 + cc] = fmaxf(red[256 + cc], red[384 + cc]);
      }
    }
  }
}

// colmax reduce: 625 partial rows -> m = [mp[512] | mr[512]], grid 4 x 256
__global__ __launch_bounds__(256) void colmax_red_k(const float* __restrict__ part,
                                                    float* __restrict__ m) {
  int idx = blockIdx.x * 256 + threadIdx.x;  // 0..1023
  int c = idx & 511;
  const float* P = part + (size_t)(idx >> 9) * (625 * 512) + c;
  float v = -1e30f;
#pragma unroll 1
  for (int b = 0; b < 625; b += 5) {
    float v0 = P[(size_t)(b + 0) * 512], v1 = P[(size_t)(b + 1) * 512];
    float v2 = P[(size_t)(b + 2) * 512], v3 = P[(size_t)(b + 3) * 512];
    float v4 = P[(size_t)(b + 4) * 512];
    v = fmaxf(v, fmaxf(fmaxf(v0, v1), fmaxf(fmaxf(v2, v3), v4)));
  }
  m[idx] = v;
}

// ---------------------------------------------------------------------------
// aggblend: per node n (one wave): z,z2 in regs over CSR in-edges; reads fp16
// EaH; writes blend fp16 to blendH; tail writes z2I. 1-ahead prefetch.
// ---------------------------------------------------------------------------
__global__ __launch_bounds__(256) void aggblend_k(const char* __restrict__ EaH,
                                                  const float* __restrict__ Na,
                                                  const char* __restrict__ exI,
                                                  const char* __restrict__ nxI,
                                                  const int* __restrict__ src,
                                                  const int* __restrict__ off,
                                                  const int* __restrict__ eid,
                                                  const float* __restrict__ mp,
                                                  const float* __restrict__ mr,
                                                  char* __restrict__ blendH,
                                                  char* __restrict__ z2I) {
  const int w = threadIdx.x >> 6, o = threadIdx.x & 63;
  int n = blockIdx.x * 4 + w;
  if (n >= NNODES) return;
  float m_p[8], m_r[8], nd[8], xd[8], z[8], z2[8];
#pragma unroll
  for (int j = 0; j < 8; j++) {
    m_p[j] = mp[o * 8 + j];
    m_r[j] = mr[o * 8 + j];
    z[j] = 0.f; z2[j] = 0.f;
  }
  {
    const float* np = Na + (size_t)n * 512 + o * 8;
    float4 d0 = *(const float4*)np, d1 = *(const float4*)(np + 4);
    nd[0] = d0.x; nd[1] = d0.y; nd[2] = d0.z; nd[3] = d0.w;
    nd[4] = d1.x; nd[5] = d1.y; nd[6] = d1.z; nd[7] = d1.w;
    unsigned short hh[8];
    unpack8(*(const uint4*)(nxI + (size_t)n * 1024 + octA(n, o)), hh);
#pragma unroll
    for (int j = 0; j < 8; j++) xd[j] = h2f(hh[j]);
  }
  const int i0 = off[n], i1 = off[n + 1];
  if (i0 < i1) {
    int e = eid[i0];
    int s = src[e];
    uint4 cea = *(const uint4*)(EaH + (size_t)e * 1024 + octA(e, o));
    const float* ns = Na + (size_t)s * 512 + o * 8;
    float4 cs0 = *(const float4*)ns, cs1 = *(const float4*)(ns + 4);
    uint4 cx = *(const uint4*)(exI + (size_t)e * 1024 + octA(e, o));
    uint4 cn = *(const uint4*)(nxI + (size_t)s * 1024 + octA(s, o));
    for (int i = i0; i < i1; i++) {
      int en = 0, sn = 0;
      float4 ps0, ps1;
      uint4 pea, px, pn;
      const bool more = (i + 1 < i1);
      if (more) {
        en = eid[i + 1];
        sn = src[en];
        pea = *(const uint4*)(EaH + (size_t)en * 1024 + octA(en, o));
        const float* ns2 = Na + (size_t)sn * 512 + o * 8;
        ps0 = *(const float4*)ns2; ps1 = *(const float4*)(ns2 + 4);
        px = *(const uint4*)(exI + (size_t)en * 1024 + octA(en, o));
        pn = *(const uint4*)(nxI + (size_t)sn * 1024 + octA(sn, o));
      }
      unsigned short eh[8], xh[8], sh[8];
      unpack8(cea, eh);
      unpack8(cx, xh);
      unpack8(cn, sh);
      float sv[8] = {cs0.x, cs0.y, cs0.z, cs0.w, cs1.x, cs1.y, cs1.z, cs1.w};
      unsigned short bh[8];
#pragma unroll
      for (int j = 0; j < 8; j++) {
        float ev = h2f(eh[j]);
        float sp = ev + nd[j] - m_p[j];
        float sr = ev + sv[j] - m_r[j];
        float ap = __expf(sp);
        float xe = h2f(xh[j]);
        z[j] += ap;
        z2[j] += ap * xe;
        float u = sr - sp;
        float evx = __expf(-fabsf(u));
        float wpos = 1.f / (1.f + evx);
        float wr = (u >= 0.f) ? wpos : 1.f - wpos;
        float xs_ = h2f(sh[j]);
        bh[j] = f2h(wr * xs_ + (1.f - wr) * xd[j]);
      }
      *(uint4*)(blendH + (size_t)e * 1024 + octA(e, o)) = pack8(bh);
      if (more) {
        e = en; s = sn;
        cea = pea; cs0 = ps0; cs1 = ps1;
        cx = px; cn = pn;
      }
    }
  }
  unsigned short zh[8];
#pragma unroll
  for (int j = 0; j < 8; j++) zh[j] = f2h(z2[j] / (z[j] + EPS));
  *(uint4*)(z2I + (size_t)n * 1024 + octA(n, o)) = pack8(zh);
}

// node_conf = nx @ Wnc ([512,55])
__global__ __launch_bounds__(256) void nodeconf_k(const float* __restrict__ nx,
                                                  const float* __restrict__ Wnc,
                                                  float* __restrict__ out) {
  int w = threadIdx.x >> 6, lane = threadIdx.x & 63;
  int n = blockIdx.x * 4 + w;
  const float* r = nx + (size_t)n * D;
  if (lane < 55) {
    float acc = 0.f;
    for (int k = 0; k < D; k++) acc = fmaf(r[k], Wnc[k * 55 + lane], acc);
    out[(size_t)n * 55 + lane] = acc;
  }
}

// edge_conf = ex @ Wec ([512,2])
__global__ __launch_bounds__(256) void edgeconf_k(const float* __restrict__ ex,
                                                  const float* __restrict__ Wec,
                                                  float* __restrict__ out) {
  int w = threadIdx.x >> 6, lane = threadIdx.x & 63;
  int e = blockIdx.x * 4 + w;
  const float* r = ex + (size_t)e * D;
  float a0 = 0.f, a1 = 0.f;
#pragma unroll
  for (int j = 0; j < 8; j++) {
    int c = lane + j * 64;
    float x = r[c];
    a0 = fmaf(x, Wec[c * 2 + 0], a0);
    a1 = fmaf(x, Wec[c * 2 + 1], a1);
  }
#pragma unroll
  for (int off = 32; off; off >>= 1) {
    a0 += __shfl_down(a0, off);
    a1 += __shfl_down(a1, off);
  }
  if (lane == 0) { out[(size_t)e * 2 + 0] = a0; out[(size_t)e * 2 + 1] = a1; }
}

extern "C" void kernel_launch(void* const* d_in, const int* in_sizes, int n_in,
                              void* d_out, int out_size, void* d_ws, size_t ws_size,
                              hipStream_t stream) {
  const float* in_nx = (const float*)d_in[0];
  const float* in_ex = (const float*)d_in[1];
  const int* src = (const int*)d_in[2];
  const int* dst = (const int*)d_in[3];
  const float* Wa = (const float*)d_in[4];
  const float* Wn = (const float*)d_in[5];
  const float* We = (const float*)d_in[6];
  const float* Wnc = (const float*)d_in[7];
  const float* Wec = (const float*)d_in[8];

  float* out = (float*)d_out;
  float* o_nx = out;
  float* o_nc = o_nx + (size_t)NNODES * D;
  float* o_ex = o_nc + (size_t)NNODES * 55;
  float* o_ec = o_ex + (size_t)NEDGES * D;

  const size_t SZ_EH = (size_t)NEDGES * 1024;   // 80 MB fp16 edge rows
  const size_t SZ_NH = (size_t)NNODES * 1024;
  const size_t SZ_NF = (size_t)NNODES * 2048;
  const size_t MATSZ = (size_t)512 * 4096;      // 2 MB per weight mat
  char* w = (char*)d_ws;
  char* EaH = w;                                // fp16 Ea
  char* blendH = w + SZ_EH;                     // fp16 blend
  char* exA = w + 2 * SZ_EH;                    // exI ping
  char* nxA = w + 3 * SZ_EH;                    // nxI ping
  float* Na = (float*)(w + 3 * SZ_EH + SZ_NH);
  char* z2I = w + 3 * SZ_EH + SZ_NH + SZ_NF;
  float* mpf = (float*)(w + 3 * SZ_EH + 2 * SZ_NH + SZ_NF);  // [mp|mr]
  char* WT = w + 3 * SZ_EH + 2 * SZ_NH + SZ_NF + 8192;
  char* csr = WT + 15 * MATSZ;
  int* cnt = (int*)csr;
  int* offp = cnt + NNODES + 8;
  int* cur = offp + NNODES + 8;
  int* eid = cur + NNODES + 8;
  float* part_p = (float*)(eid + NEDGES);       // 625*512
  float* part_r = part_p + 625 * 512;

  char* exB = (char*)o_ex;   // fp16 ping inside f32 output regions
  char* nxB = (char*)o_nx;

  // one-time prep
  wprep_k<<<dim3(8, 16, 15), 256, 0, stream>>>(Wa, Wn, We, WT);
  toF16_k<<<2048, 256, 0, stream>>>(in_ex, exA, NEDGES * 64);
  toF16_k<<<2048, 256, 0, stream>>>(in_nx, nxA, NNODES * 64);
  hipMemsetAsync(cnt, 0, NNODES * sizeof(int), stream);
  hist_k<<<(NEDGES + 255) / 256, 256, 0, stream>>>(dst, cnt);
  scan_k<<<1, 256, 0, stream>>>(cnt, offp, cur);
  scatter_k<<<(NEDGES + 255) / 256, 256, 0, stream>>>(dst, cur, eid);

  dim3 gE(4, NEDGES / 128);           // (4, 625)
  dim3 gN(4, (NNODES + 127) / 128);   // (4, 79)

  for (int l = 0; l < LAYERS; l++) {
    const char* WaT = WT + (size_t)l * MATSZ;
    const char* WnT = WT + (size_t)(5 + l) * MATSZ;
    const char* WeT = WT + (size_t)(10 + l) * MATSZ;
    char* exCur = (l & 1) ? exB : exA;
    char* exNxt = (l & 1) ? exA : exB;
    char* nxCur = (l & 1) ? nxB : nxA;
    char* nxNxt = (l & 1) ? nxA : nxB;

    // Na = nx @ Wa_bot (f32), then EaH = fp16(ex @ Wa_top) with fused colmax
    gemmI<512, false, false, false><<<gN, 256, 0, stream>>>(
        nxCur, 1024, nullptr, 0, WaT, 64, Na, NNODES, nullptr, nullptr, nullptr, nullptr, nullptr);
    gemmI<512, false, true, true><<<gE, 256, 0, stream>>>(
        exCur, 1024, nullptr, 0, WaT, 0, EaH, NEDGES, src, dst, Na, part_p, part_r);

    colmax_red_k<<<4, 256, 0, stream>>>(part_p, mpf);

    aggblend_k<<<(NNODES + 3) / 4, 256, 0, stream>>>(EaH, Na, exCur, nxCur, src,
                                                     offp, eid, mpf, mpf + 512, blendH, z2I);

    // node update: nx' = act(concat(z2, nx) @ Wn)
    if (l < 4)
      gemmI<1024, true, true, false><<<gN, 256, 0, stream>>>(
          z2I, 1024, nxCur, 1024, WnT, 0, nxNxt, NNODES, nullptr, nullptr, nullptr, nullptr, nullptr);
    else
      gemmI<1024, true, false, false><<<gN, 256, 0, stream>>>(
          z2I, 1024, nxCur, 1024, WnT, 0, o_nx, NNODES, nullptr, nullptr, nullptr, nullptr, nullptr);

    // edge update: ex' = act(concat(blend, ex) @ We)
    if (l < 4)
      gemmI<1024, true, true, false><<<gE, 256, 0, stream>>>(
          blendH, 1024, exCur, 1024, WeT, 0, exNxt, NEDGES, nullptr, nullptr, nullptr, nullptr, nullptr);
    else
      gemmI<1024, true, false, false><<<gE, 256, 0, stream>>>(
          blendH, 1024, exCur, 1024, WeT, 0, o_ex, NEDGES, nullptr, nullptr, nullptr, nullptr, nullptr);
  }

  nodeconf_k<<<NNODES / 4, 256, 0, stream>>>(o_nx, Wnc, o_nc);
  edgeconf_k<<<NEDGES / 4, 256, 0, stream>>>(o_ex, Wec, o_ec);
}

// Round 7
// 2150.757 us; speedup vs baseline: 6.6952x; 1.2835x over previous
//
#include <hip/hip_runtime.h>
#include <hip/hip_fp16.h>
#include <math.h>

#define D 512
#define NNODES 10000
#define NEDGES 80000
#define LAYERS 5
#define EPS 1e-5f

typedef _Float16 f16x8 __attribute__((ext_vector_type(8)));
typedef float f32x4 __attribute__((ext_vector_type(4)));

// ---------- fp16 helpers ----------
__device__ inline unsigned short f2h(float x) { return __half_as_ushort(__float2half(x)); }
__device__ inline float h2f(unsigned short u) { return __half2float(__ushort_as_half(u)); }
__device__ inline uint4 pack8(const unsigned short* v) {
  uint4 r;
  r.x = (unsigned)v[0] | ((unsigned)v[1] << 16);
  r.y = (unsigned)v[2] | ((unsigned)v[3] << 16);
  r.z = (unsigned)v[4] | ((unsigned)v[5] << 16);
  r.w = (unsigned)v[6] | ((unsigned)v[7] << 16);
  return r;
}
__device__ inline void unpack8(uint4 v, unsigned short* o) {
  o[0] = v.x & 0xffff; o[1] = v.x >> 16;
  o[2] = v.y & 0xffff; o[3] = v.y >> 16;
  o[4] = v.z & 0xffff; o[5] = v.z >> 16;
  o[6] = v.w & 0xffff; o[7] = v.w >> 16;
}

__device__ inline void gload16(const void* g, void* l) {
  __builtin_amdgcn_global_load_lds((const __attribute__((address_space(1))) void*)g,
                                   (__attribute__((address_space(3))) void*)l, 16, 0, 0);
}

// ---------------------------------------------------------------------------
// A-format (activations AND hi-only weights): fp16 rows; activation row =
// 1024 B (K=512), weight row = 2048 B (K=1024). Within each 64 B K-block
// (4 octets of 16 B), octet o sits at slot (o&3)^((r>>1)&3).
// Quarter-wave ds_read_b128: 2 lanes per 16B bank-class -> conflict-free.
// ---------------------------------------------------------------------------
__device__ inline int octA(int r, int o) {
  return ((o >> 2) << 6) + ((((o & 3) ^ ((r >> 1) & 3))) << 4);
}

// f32 [R][512] -> A-format fp16
__global__ __launch_bounds__(256) void toF16_k(const float* __restrict__ src,
                                               char* __restrict__ dst, int nOct) {
  for (long long i = (long long)blockIdx.x * 256 + threadIdx.x; i < nOct;
       i += (long long)gridDim.x * 256) {
    int row = (int)(i >> 6), oct = (int)(i & 63);
    const float* s = src + (size_t)row * 512 + oct * 8;
    float4 x0 = *(const float4*)s, x1 = *(const float4*)(s + 4);
    float xs[8] = {x0.x, x0.y, x0.z, x0.w, x1.x, x1.y, x1.z, x1.w};
    unsigned short h[8];
#pragma unroll
    for (int j = 0; j < 8; j++) h[j] = f2h(xs[j]);
    *(uint4*)(dst + (size_t)row * 1024 + octA(row, oct)) = pack8(h);
  }
}

// weight prep: W[1024][512] f32 (15 mats) -> WT[n=512][k=1024] hi-only fp16
__global__ __launch_bounds__(256) void wprep_k(const float* __restrict__ Wa,
                                               const float* __restrict__ Wn,
                                               const float* __restrict__ We,
                                               char* __restrict__ WT) {
  __shared__ float tile[64][65];
  int mat = blockIdx.z;
  const float* W = (mat < 5) ? Wa + (size_t)mat * 1024 * 512
                 : (mat < 10) ? Wn + (size_t)(mat - 5) * 1024 * 512
                              : We + (size_t)(mat - 10) * 1024 * 512;
  char* out = WT + (size_t)mat * 512 * 2048;
  int n0 = blockIdx.x * 64, k0 = blockIdx.y * 64;
  int t = threadIdx.x;
  int ty = t >> 2, tx = t & 3;
  const float* wr = W + (size_t)(k0 + ty) * 512 + n0 + tx * 16;
  float4 v0 = *(const float4*)(wr + 0), v1 = *(const float4*)(wr + 4);
  float4 v2 = *(const float4*)(wr + 8), v3 = *(const float4*)(wr + 12);
  float vv[16] = {v0.x, v0.y, v0.z, v0.w, v1.x, v1.y, v1.z, v1.w,
                  v2.x, v2.y, v2.z, v2.w, v3.x, v3.y, v3.z, v3.w};
#pragma unroll
  for (int j = 0; j < 16; j++) tile[ty][tx * 16 + j] = vv[j];
  __syncthreads();
#pragma unroll
  for (int p = 0; p < 2; p++) {
    int chunk = t + p * 256;
    int n = chunk >> 3, cc = chunk & 7;
    float xs[8];
#pragma unroll
    for (int j = 0; j < 8; j++) xs[j] = tile[cc * 8 + j][n];
    unsigned short h[8];
#pragma unroll
    for (int j = 0; j < 8; j++) h[j] = f2h(xs[j]);
    int ng = n0 + n;
    int kc = (k0 >> 3) + cc;   // octet index 0..127
    *(uint4*)(out + (size_t)ng * 2048 + octA(ng, kc)) = pack8(h);
  }
}

// ---------------------------------------------------------------------------
// CSR build over dst (dst fixed across layers)
// ---------------------------------------------------------------------------
__global__ __launch_bounds__(256) void hist_k(const int* __restrict__ dst, int* __restrict__ cnt) {
  int e = blockIdx.x * 256 + threadIdx.x;
  if (e < NEDGES) atomicAdd(&cnt[dst[e]], 1);
}

__global__ __launch_bounds__(256) void scan_k(const int* __restrict__ cnt,
                                              int* __restrict__ off, int* __restrict__ cur) {
  __shared__ int part[256];
  const int CH = (NNODES + 255) / 256;
  int t = threadIdx.x;
  int s = 0;
  int l0 = t * CH;
  for (int i = 0; i < CH; i++) {
    int idx = l0 + i;
    if (idx < NNODES) s += cnt[idx];
  }
  part[t] = s;
  __syncthreads();
  if (t == 0) {
    int acc = 0;
    for (int i = 0; i < 256; i++) { int v = part[i]; part[i] = acc; acc += v; }
  }
  __syncthreads();
  int acc = part[t];
  for (int i = 0; i < CH; i++) {
    int idx = l0 + i;
    if (idx < NNODES) { off[idx] = acc; cur[idx] = acc; acc += cnt[idx]; }
  }
  if (t == 255) off[NNODES] = acc;
}

__global__ __launch_bounds__(256) void scatter_k(const int* __restrict__ dst,
                                                 int* __restrict__ cur, int* __restrict__ eid) {
  int e = blockIdx.x * 256 + threadIdx.x;
  if (e < NEDGES) {
    int p = atomicAdd(&cur[dst[e]], 1);
    eid[p] = e;
  }
}

// ---------------------------------------------------------------------------
// GEMM: Y[R][512] = X@W, fp16 x fp16-hi (1 MFMA/pair), single-barrier
// double-buffered pipeline. All activation rows stride 1024 B.
// CMAX: fused per-panel column-max partials of (Y_fp16 + Na[dst]) / (+Na[src]).
// ---------------------------------------------------------------------------
template<int KT, bool ACT, bool OUT_I, bool CMAX>
__global__ __launch_bounds__(256) void gemmI(const char* __restrict__ X1,
                                             const char* __restrict__ X2,
                                             const char* __restrict__ BW, int cb0,
                                             void* __restrict__ Yout, int R,
                                             const int* __restrict__ srcI,
                                             const int* __restrict__ dstI,
                                             const float* __restrict__ Na,
                                             float* __restrict__ part_p,
                                             float* __restrict__ part_r) {
  __shared__ char smem[32768];   // [As0 8K][Bs0 8K][As1 8K][Bs1 8K]
  const int tid = threadIdx.x;
  const int lane = tid & 63, wv = tid >> 6;
  // bijective XCD chunking
  int flat = blockIdx.y * 4 + blockIdx.x;
  int total = gridDim.y * 4;
  int xcd = flat & 7, idx = flat >> 3;
  int q = total >> 3, rem = total & 7;
  int base = xcd * q + (xcd < rem ? xcd : rem);
  int f2 = base + idx;
  const int bn0 = (f2 & 3) * 128, bm0 = (f2 >> 2) * 128;
  const int r16 = lane & 15, g = lane >> 4;
  const int mo = (wv >> 1) * 64, no = (wv & 1) * 64;
  const int lr16 = lane >> 2, ls16 = (lane & 3) * 16;
  f32x4 acc[4][4];
#pragma unroll
  for (int i = 0; i < 4; i++)
#pragma unroll
    for (int j = 0; j < 4; j++) acc[i][j] = (f32x4){0.f, 0.f, 0.f, 0.f};

  // loop-invariant LDS fragment offsets (64 B rows, octA swizzle)
  int offA[4], offB[4];
#pragma unroll
  for (int mi = 0; mi < 4; mi++) {
    int row = mo + mi * 16 + r16;
    offA[mi] = row * 64 + ((g ^ ((row >> 1) & 3)) << 4);
  }
#pragma unroll
  for (int ni = 0; ni < 4; ni++) {
    int row = no + ni * 16 + r16;
    offB[ni] = row * 64 + ((g ^ ((row >> 1) & 3)) << 4);
  }

  // staging pointers (advance +64 B per K-step)
  const char* pA0;
  const char* pA1;
  const char* pB0;
  const char* pB1;
  {
    int g0 = bm0 + wv * 16 + lr16; if (g0 > R - 1) g0 = R - 1;
    int g1 = bm0 + (4 + wv) * 16 + lr16; if (g1 > R - 1) g1 = R - 1;
    pA0 = X1 + (size_t)g0 * 1024 + ls16;
    pA1 = X1 + (size_t)g1 * 1024 + ls16;
    int n0r = bn0 + wv * 16 + lr16;
    int n1r = bn0 + (4 + wv) * 16 + lr16;
    pB0 = BW + (size_t)n0r * 2048 + cb0 * 16 + ls16;
    pB1 = BW + (size_t)n1r * 2048 + cb0 * 16 + ls16;
  }

#define STAGE(buf)                                              \
  {                                                             \
    char* sb = smem + (buf) * 16384;                            \
    gload16(pA0, sb + wv * 1024);                               \
    gload16(pA1, sb + (4 + wv) * 1024);                         \
    gload16(pB0, sb + 8192 + wv * 1024);                        \
    gload16(pB1, sb + 8192 + (4 + wv) * 1024);                  \
    pA0 += 64; pA1 += 64; pB0 += 64; pB1 += 64;                 \
  }

  STAGE(0);
  __syncthreads();
  int cur = 0;
  for (int kt = 0; kt < KT; kt += 32) {
    if (kt + 32 < KT) {
      if (KT == 1024 && kt + 32 == 512) {
        int g0 = bm0 + wv * 16 + lr16; if (g0 > R - 1) g0 = R - 1;
        int g1 = bm0 + (4 + wv) * 16 + lr16; if (g1 > R - 1) g1 = R - 1;
        pA0 = X2 + (size_t)g0 * 1024 + ls16;
        pA1 = X2 + (size_t)g1 * 1024 + ls16;
      }
      STAGE(cur ^ 1);
    }
    const char* As = smem + cur * 16384;
    const char* Bs = As + 8192;
    f16x8 a[4], b[4];
#pragma unroll
    for (int mi = 0; mi < 4; mi++) a[mi] = *(const f16x8*)(As + offA[mi]);
#pragma unroll
    for (int ni = 0; ni < 4; ni++) b[ni] = *(const f16x8*)(Bs + offB[ni]);
#pragma unroll
    for (int mi = 0; mi < 4; mi++)
#pragma unroll
      for (int ni = 0; ni < 4; ni++)
        acc[mi][ni] = __builtin_amdgcn_mfma_f32_16x16x32_f16(a[mi], b[ni], acc[mi][ni], 0, 0, 0);
    __syncthreads();
    cur ^= 1;
  }
#undef STAGE

  if (!OUT_I) {
    float* Y = (float*)Yout;
#pragma unroll
    for (int mi = 0; mi < 4; mi++)
#pragma unroll
      for (int j = 0; j < 4; j++) {
        int row = bm0 + mo + mi * 16 + g * 4 + j;
        if (row < R) {
#pragma unroll
          for (int ni = 0; ni < 4; ni++) {
            float v = acc[mi][ni][j];
            if (ACT) v = (v >= 0.f) ? v : 0.01f * v;
            Y[(size_t)row * 512 + bn0 + no + ni * 16 + r16] = v;
          }
        }
      }
  } else {
    // LDS-staged A-format epilogue, two 64-row halves; optional fused colmax
    float* stg = (float*)smem;
    const int rg = tid >> 5, cq = (tid & 31) * 4;   // CMAX decomposition
    float4 mp4 = make_float4(-1e30f, -1e30f, -1e30f, -1e30f);
    float4 mr4 = mp4;
#pragma unroll
    for (int h = 0; h < 2; h++) {
      __syncthreads();
      if ((wv >> 1) == h) {
#pragma unroll
        for (int mi = 0; mi < 4; mi++)
#pragma unroll
          for (int j = 0; j < 4; j++) {
            int rl = mi * 16 + g * 4 + j;
#pragma unroll
            for (int ni = 0; ni < 4; ni++) {
              float v = acc[mi][ni][j];
              if (ACT) v = (v >= 0.f) ? v : 0.01f * v;
              stg[rl * 128 + no + ni * 16 + r16] = v;
            }
          }
      }
      __syncthreads();
#pragma unroll
      for (int qq = 0; qq < 4; qq++) {
        int idx2 = tid + qq * 256;
        int rl = idx2 >> 4, oc = idx2 & 15;
        int grow = bm0 + h * 64 + rl;
        if (grow < R) {
          unsigned short hh[8];
#pragma unroll
          for (int j = 0; j < 8; j++) hh[j] = f2h(stg[rl * 128 + oc * 8 + j]);
          int oct = (bn0 >> 3) + oc;
          *(uint4*)((char*)Yout + (size_t)grow * 1024 + octA(grow, oct)) = pack8(hh);
        }
      }
      if (CMAX) {
#pragma unroll 2
        for (int r = rg * 8; r < rg * 8 + 8; r++) {
          int grow = bm0 + h * 64 + r;
          int d = dstI[grow], s = srcI[grow];
          float4 v = *(const float4*)&stg[r * 128 + cq];
          v.x = h2f(f2h(v.x)); v.y = h2f(f2h(v.y));
          v.z = h2f(f2h(v.z)); v.w = h2f(f2h(v.w));
          float4 nd = *(const float4*)&Na[(size_t)d * 512 + bn0 + cq];
          float4 ns = *(const float4*)&Na[(size_t)s * 512 + bn0 + cq];
          mp4.x = fmaxf(mp4.x, v.x + nd.x); mp4.y = fmaxf(mp4.y, v.y + nd.y);
          mp4.z = fmaxf(mp4.z, v.z + nd.z); mp4.w = fmaxf(mp4.w, v.w + nd.w);
          mr4.x = fmaxf(mr4.x, v.x + ns.x); mr4.y = fmaxf(mr4.y, v.y + ns.y);
          mr4.z = fmaxf(mr4.z, v.z + ns.z); mr4.w = fmaxf(mr4.w, v.w + ns.w);
        }
      }
    }
    if (CMAX) {
      __syncthreads();
      float* red = (float*)smem;  // [8][128] p, then [8][128] r
      *(float4*)&red[rg * 128 + cq] = mp4;
      *(float4*)&red[1024 + rg * 128 + cq] = mr4;
      __syncthreads();
      if (tid < 128) {
        float vp = -1e30f, vr = -1e30f;
#pragma unroll
        for (int gi = 0; gi < 8; gi++) {
          vp = fmaxf(vp, red[gi * 128 + tid]);
          vr = fmaxf(vr, red[1024 + gi * 128 + tid]);
        }
        int panel = f2 >> 2;
        part_p[(size_t)panel * 512 + bn0 + tid] = vp;
        part_r[(size_t)panel * 512 + bn0 + tid] = vr;
      }
    }
  }
}

// colmax reduce: 625 partial rows -> m = [mp[512] | mr[512]], grid 4 x 256
__global__ __launch_bounds__(256) void colmax_red_k(const float* __restrict__ part,
                                                    float* __restrict__ m) {
  int idx = blockIdx.x * 256 + threadIdx.x;  // 0..1023
  int c = idx & 511;
  const float* P = part + (size_t)(idx >> 9) * (625 * 512) + c;
  float v = -1e30f;
#pragma unroll 1
  for (int b = 0; b < 625; b += 5) {
    float v0 = P[(size_t)(b + 0) * 512], v1 = P[(size_t)(b + 1) * 512];
    float v2 = P[(size_t)(b + 2) * 512], v3 = P[(size_t)(b + 3) * 512];
    float v4 = P[(size_t)(b + 4) * 512];
    v = fmaxf(v, fmaxf(fmaxf(v0, v1), fmaxf(fmaxf(v2, v3), v4)));
  }
  m[idx] = v;
}

// ---------------------------------------------------------------------------
// aggblend: per node n (one wave): z,z2 in regs over CSR in-edges; reads fp16
// EaH; writes blend fp16 to blendH; tail writes z2I. 1-ahead prefetch.
// ---------------------------------------------------------------------------
__global__ __launch_bounds__(256) void aggblend_k(const char* __restrict__ EaH,
                                                  const float* __restrict__ Na,
                                                  const char* __restrict__ exI,
                                                  const char* __restrict__ nxI,
                                                  const int* __restrict__ src,
                                                  const int* __restrict__ off,
                                                  const int* __restrict__ eid,
                                                  const float* __restrict__ mp,
                                                  const float* __restrict__ mr,
                                                  char* __restrict__ blendH,
                                                  char* __restrict__ z2I) {
  const int w = threadIdx.x >> 6, o = threadIdx.x & 63;
  int n = blockIdx.x * 4 + w;
  if (n >= NNODES) return;
  float m_p[8], m_r[8], nd[8], xd[8], z[8], z2[8];
#pragma unroll
  for (int j = 0; j < 8; j++) {
    m_p[j] = mp[o * 8 + j];
    m_r[j] = mr[o * 8 + j];
    z[j] = 0.f; z2[j] = 0.f;
  }
  {
    const float* np = Na + (size_t)n * 512 + o * 8;
    float4 d0 = *(const float4*)np, d1 = *(const float4*)(np + 4);
    nd[0] = d0.x; nd[1] = d0.y; nd[2] = d0.z; nd[3] = d0.w;
    nd[4] = d1.x; nd[5] = d1.y; nd[6] = d1.z; nd[7] = d1.w;
    unsigned short hh[8];
    unpack8(*(const uint4*)(nxI + (size_t)n * 1024 + octA(n, o)), hh);
#pragma unroll
    for (int j = 0; j < 8; j++) xd[j] = h2f(hh[j]);
  }
  const int i0 = off[n], i1 = off[n + 1];
  if (i0 < i1) {
    int e = eid[i0];
    int s = src[e];
    uint4 cea = *(const uint4*)(EaH + (size_t)e * 1024 + octA(e, o));
    const float* ns = Na + (size_t)s * 512 + o * 8;
    float4 cs0 = *(const float4*)ns, cs1 = *(const float4*)(ns + 4);
    uint4 cx = *(const uint4*)(exI + (size_t)e * 1024 + octA(e, o));
    uint4 cn = *(const uint4*)(nxI + (size_t)s * 1024 + octA(s, o));
    for (int i = i0; i < i1; i++) {
      int en = 0, sn = 0;
      float4 ps0, ps1;
      uint4 pea, px, pn;
      const bool more = (i + 1 < i1);
      if (more) {
        en = eid[i + 1];
        sn = src[en];
        pea = *(const uint4*)(EaH + (size_t)en * 1024 + octA(en, o));
        const float* ns2 = Na + (size_t)sn * 512 + o * 8;
        ps0 = *(const float4*)ns2; ps1 = *(const float4*)(ns2 + 4);
        px = *(const uint4*)(exI + (size_t)en * 1024 + octA(en, o));
        pn = *(const uint4*)(nxI + (size_t)sn * 1024 + octA(sn, o));
      }
      unsigned short eh[8], xh[8], sh[8];
      unpack8(cea, eh);
      unpack8(cx, xh);
      unpack8(cn, sh);
      float sv[8] = {cs0.x, cs0.y, cs0.z, cs0.w, cs1.x, cs1.y, cs1.z, cs1.w};
      unsigned short bh[8];
#pragma unroll
      for (int j = 0; j < 8; j++) {
        float ev = h2f(eh[j]);
        float sp = ev + nd[j] - m_p[j];
        float sr = ev + sv[j] - m_r[j];
        float ap = __expf(sp);
        float xe = h2f(xh[j]);
        z[j] += ap;
        z2[j] += ap * xe;
        float u = sr - sp;
        float evx = __expf(-fabsf(u));
        float wpos = 1.f / (1.f + evx);
        float wr = (u >= 0.f) ? wpos : 1.f - wpos;
        float xs_ = h2f(sh[j]);
        bh[j] = f2h(wr * xs_ + (1.f - wr) * xd[j]);
      }
      *(uint4*)(blendH + (size_t)e * 1024 + octA(e, o)) = pack8(bh);
      if (more) {
        e = en; s = sn;
        cea = pea; cs0 = ps0; cs1 = ps1;
        cx = px; cn = pn;
      }
    }
  }
  unsigned short zh[8];
#pragma unroll
  for (int j = 0; j < 8; j++) zh[j] = f2h(z2[j] / (z[j] + EPS));
  *(uint4*)(z2I + (size_t)n * 1024 + octA(n, o)) = pack8(zh);
}

// node_conf = nx @ Wnc ([512,55])
__global__ __launch_bounds__(256) void nodeconf_k(const float* __restrict__ nx,
                                                  const float* __restrict__ Wnc,
                                                  float* __restrict__ out) {
  int w = threadIdx.x >> 6, lane = threadIdx.x & 63;
  int n = blockIdx.x * 4 + w;
  const float* r = nx + (size_t)n * D;
  if (lane < 55) {
    float acc = 0.f;
    for (int k = 0; k < D; k++) acc = fmaf(r[k], Wnc[k * 55 + lane], acc);
    out[(size_t)n * 55 + lane] = acc;
  }
}

// edge_conf = ex @ Wec ([512,2])
__global__ __launch_bounds__(256) void edgeconf_k(const float* __restrict__ ex,
                                                  const float* __restrict__ Wec,
                                                  float* __restrict__ out) {
  int w = threadIdx.x >> 6, lane = threadIdx.x & 63;
  int e = blockIdx.x * 4 + w;
  const float* r = ex + (size_t)e * D;
  float a0 = 0.f, a1 = 0.f;
#pragma unroll
  for (int j = 0; j < 8; j++) {
    int c = lane + j * 64;
    float x = r[c];
    a0 = fmaf(x, Wec[c * 2 + 0], a0);
    a1 = fmaf(x, Wec[c * 2 + 1], a1);
  }
#pragma unroll
  for (int off = 32; off; off >>= 1) {
    a0 += __shfl_down(a0, off);
    a1 += __shfl_down(a1, off);
  }
  if (lane == 0) { out[(size_t)e * 2 + 0] = a0; out[(size_t)e * 2 + 1] = a1; }
}

extern "C" void kernel_launch(void* const* d_in, const int* in_sizes, int n_in,
                              void* d_out, int out_size, void* d_ws, size_t ws_size,
                              hipStream_t stream) {
  const float* in_nx = (const float*)d_in[0];
  const float* in_ex = (const float*)d_in[1];
  const int* src = (const int*)d_in[2];
  const int* dst = (const int*)d_in[3];
  const float* Wa = (const float*)d_in[4];
  const float* Wn = (const float*)d_in[5];
  const float* We = (const float*)d_in[6];
  const float* Wnc = (const float*)d_in[7];
  const float* Wec = (const float*)d_in[8];

  float* out = (float*)d_out;
  float* o_nx = out;
  float* o_nc = o_nx + (size_t)NNODES * D;
  float* o_ex = o_nc + (size_t)NNODES * 55;
  float* o_ec = o_ex + (size_t)NEDGES * D;

  const size_t SZ_EH = (size_t)NEDGES * 1024;   // 80 MB fp16 edge rows
  const size_t SZ_NH = (size_t)NNODES * 1024;
  const size_t SZ_NF = (size_t)NNODES * 2048;
  const size_t MATSZ = (size_t)512 * 2048;      // 1 MB per weight mat (hi-only)
  char* w = (char*)d_ws;
  char* EaH = w;                                // fp16 Ea
  char* blendH = w + SZ_EH;                     // fp16 blend
  char* exA = w + 2 * SZ_EH;                    // exI ping
  char* nxA = w + 3 * SZ_EH;                    // nxI ping
  float* Na = (float*)(w + 3 * SZ_EH + SZ_NH);
  char* z2I = w + 3 * SZ_EH + SZ_NH + SZ_NF;
  float* mpf = (float*)(w + 3 * SZ_EH + 2 * SZ_NH + SZ_NF);  // [mp|mr]
  char* WT = w + 3 * SZ_EH + 2 * SZ_NH + SZ_NF + 8192;
  char* csr = WT + 15 * MATSZ;
  int* cnt = (int*)csr;
  int* offp = cnt + NNODES + 8;
  int* cur = offp + NNODES + 8;
  int* eid = cur + NNODES + 8;
  float* part_p = (float*)(eid + NEDGES);       // 625*512
  float* part_r = part_p + 625 * 512;

  char* exB = (char*)o_ex;   // fp16 ping inside f32 output regions
  char* nxB = (char*)o_nx;

  // one-time prep
  wprep_k<<<dim3(8, 16, 15), 256, 0, stream>>>(Wa, Wn, We, WT);
  toF16_k<<<2048, 256, 0, stream>>>(in_ex, exA, NEDGES * 64);
  toF16_k<<<2048, 256, 0, stream>>>(in_nx, nxA, NNODES * 64);
  hipMemsetAsync(cnt, 0, NNODES * sizeof(int), stream);
  hist_k<<<(NEDGES + 255) / 256, 256, 0, stream>>>(dst, cnt);
  scan_k<<<1, 256, 0, stream>>>(cnt, offp, cur);
  scatter_k<<<(NEDGES + 255) / 256, 256, 0, stream>>>(dst, cur, eid);

  dim3 gE(4, NEDGES / 128);           // (4, 625)
  dim3 gN(4, (NNODES + 127) / 128);   // (4, 79)

  for (int l = 0; l < LAYERS; l++) {
    const char* WaT = WT + (size_t)l * MATSZ;
    const char* WnT = WT + (size_t)(5 + l) * MATSZ;
    const char* WeT = WT + (size_t)(10 + l) * MATSZ;
    char* exCur = (l & 1) ? exB : exA;
    char* exNxt = (l & 1) ? exA : exB;
    char* nxCur = (l & 1) ? nxB : nxA;
    char* nxNxt = (l & 1) ? nxA : nxB;

    // Na = nx @ Wa_bot (f32), then EaH = fp16(ex @ Wa_top) with fused colmax
    gemmI<512, false, false, false><<<gN, 256, 0, stream>>>(
        nxCur, nullptr, WaT, 64, Na, NNODES, nullptr, nullptr, nullptr, nullptr, nullptr);
    gemmI<512, false, true, true><<<gE, 256, 0, stream>>>(
        exCur, nullptr, WaT, 0, EaH, NEDGES, src, dst, Na, part_p, part_r);

    colmax_red_k<<<4, 256, 0, stream>>>(part_p, mpf);

    aggblend_k<<<(NNODES + 3) / 4, 256, 0, stream>>>(EaH, Na, exCur, nxCur, src,
                                                     offp, eid, mpf, mpf + 512, blendH, z2I);

    // node update: nx' = act(concat(z2, nx) @ Wn)
    if (l < 4)
      gemmI<1024, true, true, false><<<gN, 256, 0, stream>>>(
          z2I, nxCur, WnT, 0, nxNxt, NNODES, nullptr, nullptr, nullptr, nullptr, nullptr);
    else
      gemmI<1024, true, false, false><<<gN, 256, 0, stream>>>(
          z2I, nxCur, WnT, 0, o_nx, NNODES, nullptr, nullptr, nullptr, nullptr, nullptr);

    // edge update: ex' = act(concat(blend, ex) @ We)
    if (l < 4)
      gemmI<1024, true, true, false><<<gE, 256, 0, stream>>>(
          blendH, exCur, WeT, 0, exNxt, NEDGES, nullptr, nullptr, nullptr, nullptr, nullptr);
    else
      gemmI<1024, true, false, false><<<gE, 256, 0, stream>>>(
          blendH, exCur, WeT, 0, o_ex, NEDGES, nullptr, nullptr, nullptr, nullptr, nullptr);
  }

  nodeconf_k<<<NNODES / 4, 256, 0, stream>>>(o_nx, Wnc, o_nc);
  edgeconf_k<<<NEDGES / 4, 256, 0, stream>>>(o_ex, Wec, o_ec);
}

// Round 8
// 2079.988 us; speedup vs baseline: 6.9230x; 1.0340x over previous
//
#include <hip/hip_runtime.h>
#include <hip/hip_fp16.h>
#include <math.h>

#define D 512
#define NNODES 10000
#define NEDGES 80000
#define LAYERS 5
#define EPS 1e-5f

typedef _Float16 f16x8 __attribute__((ext_vector_type(8)));
typedef float f32x4 __attribute__((ext_vector_type(4)));

// ---------- fp16 helpers ----------
__device__ inline unsigned short f2h(float x) { return __half_as_ushort(__float2half(x)); }
__device__ inline float h2f(unsigned short u) { return __half2float(__ushort_as_half(u)); }
__device__ inline uint4 pack8(const unsigned short* v) {
  uint4 r;
  r.x = (unsigned)v[0] | ((unsigned)v[1] << 16);
  r.y = (unsigned)v[2] | ((unsigned)v[3] << 16);
  r.z = (unsigned)v[4] | ((unsigned)v[5] << 16);
  r.w = (unsigned)v[6] | ((unsigned)v[7] << 16);
  return r;
}
__device__ inline void unpack8(uint4 v, unsigned short* o) {
  o[0] = v.x & 0xffff; o[1] = v.x >> 16;
  o[2] = v.y & 0xffff; o[3] = v.y >> 16;
  o[4] = v.z & 0xffff; o[5] = v.z >> 16;
  o[6] = v.w & 0xffff; o[7] = v.w >> 16;
}

__device__ inline void gload16(const void* g, void* l) {
  __builtin_amdgcn_global_load_lds((const __attribute__((address_space(1))) void*)g,
                                   (__attribute__((address_space(3))) void*)l, 16, 0, 0);
}

// ---------------------------------------------------------------------------
// A-format (activations AND hi-only weights): fp16 rows; activation row =
// 1024 B (K=512), weight row = 2048 B (K=1024). Within each 64 B K-block
// (4 octets of 16 B), octet o sits at slot (o&3)^((r>>1)&3).
// Quarter-wave ds_read_b128: 2 lanes per 16B bank-class -> conflict-free.
// ---------------------------------------------------------------------------
__device__ inline int octA(int r, int o) {
  return ((o >> 2) << 6) + ((((o & 3) ^ ((r >> 1) & 3))) << 4);
}

// f32 [R][512] -> A-format fp16
__global__ __launch_bounds__(256) void toF16_k(const float* __restrict__ src,
                                               char* __restrict__ dst, int nOct) {
  for (long long i = (long long)blockIdx.x * 256 + threadIdx.x; i < nOct;
       i += (long long)gridDim.x * 256) {
    int row = (int)(i >> 6), oct = (int)(i & 63);
    const float* s = src + (size_t)row * 512 + oct * 8;
    float4 x0 = *(const float4*)s, x1 = *(const float4*)(s + 4);
    float xs[8] = {x0.x, x0.y, x0.z, x0.w, x1.x, x1.y, x1.z, x1.w};
    unsigned short h[8];
#pragma unroll
    for (int j = 0; j < 8; j++) h[j] = f2h(xs[j]);
    *(uint4*)(dst + (size_t)row * 1024 + octA(row, oct)) = pack8(h);
  }
}

// weight prep: W[1024][512] f32 (15 mats) -> WT[n=512][k=1024] hi-only fp16
__global__ __launch_bounds__(256) void wprep_k(const float* __restrict__ Wa,
                                               const float* __restrict__ Wn,
                                               const float* __restrict__ We,
                                               char* __restrict__ WT) {
  __shared__ float tile[64][65];
  int mat = blockIdx.z;
  const float* W = (mat < 5) ? Wa + (size_t)mat * 1024 * 512
                 : (mat < 10) ? Wn + (size_t)(mat - 5) * 1024 * 512
                              : We + (size_t)(mat - 10) * 1024 * 512;
  char* out = WT + (size_t)mat * 512 * 2048;
  int n0 = blockIdx.x * 64, k0 = blockIdx.y * 64;
  int t = threadIdx.x;
  int ty = t >> 2, tx = t & 3;
  const float* wr = W + (size_t)(k0 + ty) * 512 + n0 + tx * 16;
  float4 v0 = *(const float4*)(wr + 0), v1 = *(const float4*)(wr + 4);
  float4 v2 = *(const float4*)(wr + 8), v3 = *(const float4*)(wr + 12);
  float vv[16] = {v0.x, v0.y, v0.z, v0.w, v1.x, v1.y, v1.z, v1.w,
                  v2.x, v2.y, v2.z, v2.w, v3.x, v3.y, v3.z, v3.w};
#pragma unroll
  for (int j = 0; j < 16; j++) tile[ty][tx * 16 + j] = vv[j];
  __syncthreads();
#pragma unroll
  for (int p = 0; p < 2; p++) {
    int chunk = t + p * 256;
    int n = chunk >> 3, cc = chunk & 7;
    float xs[8];
#pragma unroll
    for (int j = 0; j < 8; j++) xs[j] = tile[cc * 8 + j][n];
    unsigned short h[8];
#pragma unroll
    for (int j = 0; j < 8; j++) h[j] = f2h(xs[j]);
    int ng = n0 + n;
    int kc = (k0 >> 3) + cc;   // octet index 0..127
    *(uint4*)(out + (size_t)ng * 2048 + octA(ng, kc)) = pack8(h);
  }
}

// ---------------------------------------------------------------------------
// CSR build over dst (dst fixed across layers)
// ---------------------------------------------------------------------------
__global__ __launch_bounds__(256) void hist_k(const int* __restrict__ dst, int* __restrict__ cnt) {
  int e = blockIdx.x * 256 + threadIdx.x;
  if (e < NEDGES) atomicAdd(&cnt[dst[e]], 1);
}

__global__ __launch_bounds__(256) void scan_k(const int* __restrict__ cnt,
                                              int* __restrict__ off, int* __restrict__ cur) {
  __shared__ int part[256];
  const int CH = (NNODES + 255) / 256;
  int t = threadIdx.x;
  int s = 0;
  int l0 = t * CH;
  for (int i = 0; i < CH; i++) {
    int idx = l0 + i;
    if (idx < NNODES) s += cnt[idx];
  }
  part[t] = s;
  __syncthreads();
  if (t == 0) {
    int acc = 0;
    for (int i = 0; i < 256; i++) { int v = part[i]; part[i] = acc; acc += v; }
  }
  __syncthreads();
  int acc = part[t];
  for (int i = 0; i < CH; i++) {
    int idx = l0 + i;
    if (idx < NNODES) { off[idx] = acc; cur[idx] = acc; acc += cnt[idx]; }
  }
  if (t == 255) off[NNODES] = acc;
}

__global__ __launch_bounds__(256) void scatter_k(const int* __restrict__ dst,
                                                 int* __restrict__ cur, int* __restrict__ eid) {
  int e = blockIdx.x * 256 + threadIdx.x;
  if (e < NEDGES) {
    int p = atomicAdd(&cur[dst[e]], 1);
    eid[p] = e;
  }
}

// ---------------------------------------------------------------------------
// GEMM: Y[R][512] = X@W, fp16 x fp16-hi. 3-buffer ring, depth-2 prefetch,
// counted vmcnt(4) + raw s_barrier (T3+T4), setprio around MFMA (T5).
// ---------------------------------------------------------------------------
template<int KT, bool ACT, bool OUT_I, bool CMAX>
__global__ __launch_bounds__(256) void gemmI(const char* __restrict__ X1,
                                             const char* __restrict__ X2,
                                             const char* __restrict__ BW, int cb0,
                                             void* __restrict__ Yout, int R,
                                             const int* __restrict__ srcI,
                                             const int* __restrict__ dstI,
                                             const float* __restrict__ Na,
                                             float* __restrict__ part_p,
                                             float* __restrict__ part_r) {
  __shared__ char smem[49152];   // 3 x [As 8K | Bs 8K]
  const int tid = threadIdx.x;
  const int lane = tid & 63, wv = tid >> 6;
  const int NT = KT / 32;
  // bijective XCD chunking
  int flat = blockIdx.y * 4 + blockIdx.x;
  int total = gridDim.y * 4;
  int xcd = flat & 7, idx = flat >> 3;
  int q = total >> 3, rem = total & 7;
  int base = xcd * q + (xcd < rem ? xcd : rem);
  int f2 = base + idx;
  const int bn0 = (f2 & 3) * 128, bm0 = (f2 >> 2) * 128;
  const int r16 = lane & 15, g = lane >> 4;
  const int mo = (wv >> 1) * 64, no = (wv & 1) * 64;
  const int lr16 = lane >> 2, ls16 = (lane & 3) * 16;
  f32x4 acc[4][4];
#pragma unroll
  for (int i = 0; i < 4; i++)
#pragma unroll
    for (int j = 0; j < 4; j++) acc[i][j] = (f32x4){0.f, 0.f, 0.f, 0.f};

  // loop-invariant LDS fragment offsets (64 B rows, octA swizzle)
  int offA[4], offB[4];
#pragma unroll
  for (int mi = 0; mi < 4; mi++) {
    int row = mo + mi * 16 + r16;
    offA[mi] = row * 64 + ((g ^ ((row >> 1) & 3)) << 4);
  }
#pragma unroll
  for (int ni = 0; ni < 4; ni++) {
    int row = no + ni * 16 + r16;
    offB[ni] = row * 64 + ((g ^ ((row >> 1) & 3)) << 4);
  }

  // staging pointers (advance +64 B per stage)
  const char* pA0;
  const char* pA1;
  const char* pB0;
  const char* pB1;
  {
    int g0 = bm0 + wv * 16 + lr16; if (g0 > R - 1) g0 = R - 1;
    int g1 = bm0 + (4 + wv) * 16 + lr16; if (g1 > R - 1) g1 = R - 1;
    pA0 = X1 + (size_t)g0 * 1024 + ls16;
    pA1 = X1 + (size_t)g1 * 1024 + ls16;
    int n0r = bn0 + wv * 16 + lr16;
    int n1r = bn0 + (4 + wv) * 16 + lr16;
    pB0 = BW + (size_t)n0r * 2048 + cb0 * 16 + ls16;
    pB1 = BW + (size_t)n1r * 2048 + cb0 * 16 + ls16;
  }

  int us = 0;  // next stage index to issue
#define STAGE()                                                 \
  {                                                             \
    char* sb = smem + (us % 3) * 16384;                         \
    gload16(pA0, sb + wv * 1024);                               \
    gload16(pA1, sb + (4 + wv) * 1024);                         \
    gload16(pB0, sb + 8192 + wv * 1024);                        \
    gload16(pB1, sb + 8192 + (4 + wv) * 1024);                  \
    pA0 += 64; pA1 += 64; pB0 += 64; pB1 += 64;                 \
    us++;                                                       \
  }

  STAGE();   // stage 0
  STAGE();   // stage 1  (8 loads in flight)
  for (int t = 0; t < NT; ++t) {
    if (t + 1 < NT) {
      asm volatile("s_waitcnt vmcnt(4)" ::: "memory");   // oldest stage landed
    } else {
      asm volatile("s_waitcnt vmcnt(0)" ::: "memory");
    }
    __builtin_amdgcn_s_barrier();                        // all waves: buf t ready
    if (us < NT) {
      if (KT == 1024 && us == 16) {
        int g0 = bm0 + wv * 16 + lr16; if (g0 > R - 1) g0 = R - 1;
        int g1 = bm0 + (4 + wv) * 16 + lr16; if (g1 > R - 1) g1 = R - 1;
        pA0 = X2 + (size_t)g0 * 1024 + ls16;
        pA1 = X2 + (size_t)g1 * 1024 + ls16;
      }
      STAGE();
    }
    const char* As = smem + (t % 3) * 16384;
    const char* Bs = As + 8192;
    f16x8 a[4], b[4];
#pragma unroll
    for (int mi = 0; mi < 4; mi++) a[mi] = *(const f16x8*)(As + offA[mi]);
#pragma unroll
    for (int ni = 0; ni < 4; ni++) b[ni] = *(const f16x8*)(Bs + offB[ni]);
    __builtin_amdgcn_s_setprio(1);
#pragma unroll
    for (int mi = 0; mi < 4; mi++)
#pragma unroll
      for (int ni = 0; ni < 4; ni++)
        acc[mi][ni] = __builtin_amdgcn_mfma_f32_16x16x32_f16(a[mi], b[ni], acc[mi][ni], 0, 0, 0);
    __builtin_amdgcn_s_setprio(0);
  }
#undef STAGE

  if (!OUT_I) {
    float* Y = (float*)Yout;
#pragma unroll
    for (int mi = 0; mi < 4; mi++)
#pragma unroll
      for (int j = 0; j < 4; j++) {
        int row = bm0 + mo + mi * 16 + g * 4 + j;
        if (row < R) {
#pragma unroll
          for (int ni = 0; ni < 4; ni++) {
            float v = acc[mi][ni][j];
            if (ACT) v = (v >= 0.f) ? v : 0.01f * v;
            Y[(size_t)row * 512 + bn0 + no + ni * 16 + r16] = v;
          }
        }
      }
  } else {
    // LDS-staged A-format epilogue, two 64-row halves; optional fused colmax
    float* stg = (float*)smem;
    const int rg = tid >> 5, cq = (tid & 31) * 4;   // CMAX decomposition
    float4 mp4 = make_float4(-1e30f, -1e30f, -1e30f, -1e30f);
    float4 mr4 = mp4;
#pragma unroll
    for (int h = 0; h < 2; h++) {
      __syncthreads();
      if ((wv >> 1) == h) {
#pragma unroll
        for (int mi = 0; mi < 4; mi++)
#pragma unroll
          for (int j = 0; j < 4; j++) {
            int rl = mi * 16 + g * 4 + j;
#pragma unroll
            for (int ni = 0; ni < 4; ni++) {
              float v = acc[mi][ni][j];
              if (ACT) v = (v >= 0.f) ? v : 0.01f * v;
              stg[rl * 128 + no + ni * 16 + r16] = v;
            }
          }
      }
      __syncthreads();
#pragma unroll
      for (int qq = 0; qq < 4; qq++) {
        int idx2 = tid + qq * 256;
        int rl = idx2 >> 4, oc = idx2 & 15;
        int grow = bm0 + h * 64 + rl;
        if (grow < R) {
          unsigned short hh[8];
#pragma unroll
          for (int j = 0; j < 8; j++) hh[j] = f2h(stg[rl * 128 + oc * 8 + j]);
          int oct = (bn0 >> 3) + oc;
          *(uint4*)((char*)Yout + (size_t)grow * 1024 + octA(grow, oct)) = pack8(hh);
        }
      }
      if (CMAX) {
#pragma unroll 2
        for (int r = rg * 8; r < rg * 8 + 8; r++) {
          int grow = bm0 + h * 64 + r;
          int d = dstI[grow], s = srcI[grow];
          float4 v = *(const float4*)&stg[r * 128 + cq];
          v.x = h2f(f2h(v.x)); v.y = h2f(f2h(v.y));
          v.z = h2f(f2h(v.z)); v.w = h2f(f2h(v.w));
          float4 nd = *(const float4*)&Na[(size_t)d * 512 + bn0 + cq];
          float4 ns = *(const float4*)&Na[(size_t)s * 512 + bn0 + cq];
          mp4.x = fmaxf(mp4.x, v.x + nd.x); mp4.y = fmaxf(mp4.y, v.y + nd.y);
          mp4.z = fmaxf(mp4.z, v.z + nd.z); mp4.w = fmaxf(mp4.w, v.w + nd.w);
          mr4.x = fmaxf(mr4.x, v.x + ns.x); mr4.y = fmaxf(mr4.y, v.y + ns.y);
          mr4.z = fmaxf(mr4.z, v.z + ns.z); mr4.w = fmaxf(mr4.w, v.w + ns.w);
        }
      }
    }
    if (CMAX) {
      __syncthreads();
      float* red = (float*)smem;  // [8][128] p, then [8][128] r
      *(float4*)&red[rg * 128 + cq] = mp4;
      *(float4*)&red[1024 + rg * 128 + cq] = mr4;
      __syncthreads();
      if (tid < 128) {
        float vp = -1e30f, vr = -1e30f;
#pragma unroll
        for (int gi = 0; gi < 8; gi++) {
          vp = fmaxf(vp, red[gi * 128 + tid]);
          vr = fmaxf(vr, red[1024 + gi * 128 + tid]);
        }
        int panel = f2 >> 2;
        part_p[(size_t)panel * 512 + bn0 + tid] = vp;
        part_r[(size_t)panel * 512 + bn0 + tid] = vr;
      }
    }
  }
}

// colmax reduce: 625 partial rows -> m = [mp[512] | mr[512]], grid 4 x 256
__global__ __launch_bounds__(256) void colmax_red_k(const float* __restrict__ part,
                                                    float* __restrict__ m) {
  int idx = blockIdx.x * 256 + threadIdx.x;  // 0..1023
  int c = idx & 511;
  const float* P = part + (size_t)(idx >> 9) * (625 * 512) + c;
  float v = -1e30f;
#pragma unroll 1
  for (int b = 0; b < 625; b += 5) {
    float v0 = P[(size_t)(b + 0) * 512], v1 = P[(size_t)(b + 1) * 512];
    float v2 = P[(size_t)(b + 2) * 512], v3 = P[(size_t)(b + 3) * 512];
    float v4 = P[(size_t)(b + 4) * 512];
    v = fmaxf(v, fmaxf(fmaxf(v0, v1), fmaxf(fmaxf(v2, v3), v4)));
  }
  m[idx] = v;
}

// ---------------------------------------------------------------------------
// aggblend: per node n (one wave): z,z2 in regs over CSR in-edges; reads fp16
// EaH; writes blend fp16 to blendH; tail writes z2I. 1-ahead prefetch.
// ---------------------------------------------------------------------------
__global__ __launch_bounds__(256) void aggblend_k(const char* __restrict__ EaH,
                                                  const float* __restrict__ Na,
                                                  const char* __restrict__ exI,
                                                  const char* __restrict__ nxI,
                                                  const int* __restrict__ src,
                                                  const int* __restrict__ off,
                                                  const int* __restrict__ eid,
                                                  const float* __restrict__ mp,
                                                  const float* __restrict__ mr,
                                                  char* __restrict__ blendH,
                                                  char* __restrict__ z2I) {
  const int w = threadIdx.x >> 6, o = threadIdx.x & 63;
  int n = blockIdx.x * 4 + w;
  if (n >= NNODES) return;
  float m_p[8], m_r[8], nd[8], xd[8], z[8], z2[8];
#pragma unroll
  for (int j = 0; j < 8; j++) {
    m_p[j] = mp[o * 8 + j];
    m_r[j] = mr[o * 8 + j];
    z[j] = 0.f; z2[j] = 0.f;
  }
  {
    const float* np = Na + (size_t)n * 512 + o * 8;
    float4 d0 = *(const float4*)np, d1 = *(const float4*)(np + 4);
    nd[0] = d0.x; nd[1] = d0.y; nd[2] = d0.z; nd[3] = d0.w;
    nd[4] = d1.x; nd[5] = d1.y; nd[6] = d1.z; nd[7] = d1.w;
    unsigned short hh[8];
    unpack8(*(const uint4*)(nxI + (size_t)n * 1024 + octA(n, o)), hh);
#pragma unroll
    for (int j = 0; j < 8; j++) xd[j] = h2f(hh[j]);
  }
  const int i0 = off[n], i1 = off[n + 1];
  if (i0 < i1) {
    int e = eid[i0];
    int s = src[e];
    uint4 cea = *(const uint4*)(EaH + (size_t)e * 1024 + octA(e, o));
    const float* ns = Na + (size_t)s * 512 + o * 8;
    float4 cs0 = *(const float4*)ns, cs1 = *(const float4*)(ns + 4);
    uint4 cx = *(const uint4*)(exI + (size_t)e * 1024 + octA(e, o));
    uint4 cn = *(const uint4*)(nxI + (size_t)s * 1024 + octA(s, o));
    for (int i = i0; i < i1; i++) {
      int en = 0, sn = 0;
      float4 ps0, ps1;
      uint4 pea, px, pn;
      const bool more = (i + 1 < i1);
      if (more) {
        en = eid[i + 1];
        sn = src[en];
        pea = *(const uint4*)(EaH + (size_t)en * 1024 + octA(en, o));
        const float* ns2 = Na + (size_t)sn * 512 + o * 8;
        ps0 = *(const float4*)ns2; ps1 = *(const float4*)(ns2 + 4);
        px = *(const uint4*)(exI + (size_t)en * 1024 + octA(en, o));
        pn = *(const uint4*)(nxI + (size_t)sn * 1024 + octA(sn, o));
      }
      unsigned short eh[8], xh[8], sh[8];
      unpack8(cea, eh);
      unpack8(cx, xh);
      unpack8(cn, sh);
      float sv[8] = {cs0.x, cs0.y, cs0.z, cs0.w, cs1.x, cs1.y, cs1.z, cs1.w};
      unsigned short bh[8];
#pragma unroll
      for (int j = 0; j < 8; j++) {
        float ev = h2f(eh[j]);
        float sp = ev + nd[j] - m_p[j];
        float sr = ev + sv[j] - m_r[j];
        float ap = __expf(sp);
        float xe = h2f(xh[j]);
        z[j] += ap;
        z2[j] += ap * xe;
        float u = sr - sp;
        float evx = __expf(-fabsf(u));
        float wpos = 1.f / (1.f + evx);
        float wr = (u >= 0.f) ? wpos : 1.f - wpos;
        float xs_ = h2f(sh[j]);
        bh[j] = f2h(wr * xs_ + (1.f - wr) * xd[j]);
      }
      *(uint4*)(blendH + (size_t)e * 1024 + octA(e, o)) = pack8(bh);
      if (more) {
        e = en; s = sn;
        cea = pea; cs0 = ps0; cs1 = ps1;
        cx = px; cn = pn;
      }
    }
  }
  unsigned short zh[8];
#pragma unroll
  for (int j = 0; j < 8; j++) zh[j] = f2h(z2[j] / (z[j] + EPS));
  *(uint4*)(z2I + (size_t)n * 1024 + octA(n, o)) = pack8(zh);
}

// node_conf = nx @ Wnc ([512,55])
__global__ __launch_bounds__(256) void nodeconf_k(const float* __restrict__ nx,
                                                  const float* __restrict__ Wnc,
                                                  float* __restrict__ out) {
  int w = threadIdx.x >> 6, lane = threadIdx.x & 63;
  int n = blockIdx.x * 4 + w;
  const float* r = nx + (size_t)n * D;
  if (lane < 55) {
    float acc = 0.f;
    for (int k = 0; k < D; k++) acc = fmaf(r[k], Wnc[k * 55 + lane], acc);
    out[(size_t)n * 55 + lane] = acc;
  }
}

// edge_conf = ex @ Wec ([512,2])
__global__ __launch_bounds__(256) void edgeconf_k(const float* __restrict__ ex,
                                                  const float* __restrict__ Wec,
                                                  float* __restrict__ out) {
  int w = threadIdx.x >> 6, lane = threadIdx.x & 63;
  int e = blockIdx.x * 4 + w;
  const float* r = ex + (size_t)e * D;
  float a0 = 0.f, a1 = 0.f;
#pragma unroll
  for (int j = 0; j < 8; j++) {
    int c = lane + j * 64;
    float x = r[c];
    a0 = fmaf(x, Wec[c * 2 + 0], a0);
    a1 = fmaf(x, Wec[c * 2 + 1], a1);
  }
#pragma unroll
  for (int off = 32; off; off >>= 1) {
    a0 += __shfl_down(a0, off);
    a1 += __shfl_down(a1, off);
  }
  if (lane == 0) { out[(size_t)e * 2 + 0] = a0; out[(size_t)e * 2 + 1] = a1; }
}

extern "C" void kernel_launch(void* const* d_in, const int* in_sizes, int n_in,
                              void* d_out, int out_size, void* d_ws, size_t ws_size,
                              hipStream_t stream) {
  const float* in_nx = (const float*)d_in[0];
  const float* in_ex = (const float*)d_in[1];
  const int* src = (const int*)d_in[2];
  const int* dst = (const int*)d_in[3];
  const float* Wa = (const float*)d_in[4];
  const float* Wn = (const float*)d_in[5];
  const float* We = (const float*)d_in[6];
  const float* Wnc = (const float*)d_in[7];
  const float* Wec = (const float*)d_in[8];

  float* out = (float*)d_out;
  float* o_nx = out;
  float* o_nc = o_nx + (size_t)NNODES * D;
  float* o_ex = o_nc + (size_t)NNODES * 55;
  float* o_ec = o_ex + (size_t)NEDGES * D;

  const size_t SZ_EH = (size_t)NEDGES * 1024;   // 80 MB fp16 edge rows
  const size_t SZ_NH = (size_t)NNODES * 1024;
  const size_t SZ_NF = (size_t)NNODES * 2048;
  const size_t MATSZ = (size_t)512 * 2048;      // 1 MB per weight mat (hi-only)
  char* w = (char*)d_ws;
  char* EaH = w;                                // fp16 Ea
  char* blendH = w + SZ_EH;                     // fp16 blend
  char* exA = w + 2 * SZ_EH;                    // exI ping
  char* nxA = w + 3 * SZ_EH;                    // nxI ping
  float* Na = (float*)(w + 3 * SZ_EH + SZ_NH);
  char* z2I = w + 3 * SZ_EH + SZ_NH + SZ_NF;
  float* mpf = (float*)(w + 3 * SZ_EH + 2 * SZ_NH + SZ_NF);  // [mp|mr]
  char* WT = w + 3 * SZ_EH + 2 * SZ_NH + SZ_NF + 8192;
  char* csr = WT + 15 * MATSZ;
  int* cnt = (int*)csr;
  int* offp = cnt + NNODES + 8;
  int* cur = offp + NNODES + 8;
  int* eid = cur + NNODES + 8;
  float* part_p = (float*)(eid + NEDGES);       // 625*512
  float* part_r = part_p + 625 * 512;

  char* exB = (char*)o_ex;   // fp16 ping inside f32 output regions
  char* nxB = (char*)o_nx;

  // one-time prep
  wprep_k<<<dim3(8, 16, 15), 256, 0, stream>>>(Wa, Wn, We, WT);
  toF16_k<<<2048, 256, 0, stream>>>(in_ex, exA, NEDGES * 64);
  toF16_k<<<2048, 256, 0, stream>>>(in_nx, nxA, NNODES * 64);
  hipMemsetAsync(cnt, 0, NNODES * sizeof(int), stream);
  hist_k<<<(NEDGES + 255) / 256, 256, 0, stream>>>(dst, cnt);
  scan_k<<<1, 256, 0, stream>>>(cnt, offp, cur);
  scatter_k<<<(NEDGES + 255) / 256, 256, 0, stream>>>(dst, cur, eid);

  dim3 gE(4, NEDGES / 128);           // (4, 625)
  dim3 gN(4, (NNODES + 127) / 128);   // (4, 79)

  for (int l = 0; l < LAYERS; l++) {
    const char* WaT = WT + (size_t)l * MATSZ;
    const char* WnT = WT + (size_t)(5 + l) * MATSZ;
    const char* WeT = WT + (size_t)(10 + l) * MATSZ;
    char* exCur = (l & 1) ? exB : exA;
    char* exNxt = (l & 1) ? exA : exB;
    char* nxCur = (l & 1) ? nxB : nxA;
    char* nxNxt = (l & 1) ? nxA : nxB;

    // Na = nx @ Wa_bot (f32), then EaH = fp16(ex @ Wa_top) with fused colmax
    gemmI<512, false, false, false><<<gN, 256, 0, stream>>>(
        nxCur, nullptr, WaT, 64, Na, NNODES, nullptr, nullptr, nullptr, nullptr, nullptr);
    gemmI<512, false, true, true><<<gE, 256, 0, stream>>>(
        exCur, nullptr, WaT, 0, EaH, NEDGES, src, dst, Na, part_p, part_r);

    colmax_red_k<<<4, 256, 0, stream>>>(part_p, mpf);

    aggblend_k<<<(NNODES + 3) / 4, 256, 0, stream>>>(EaH, Na, exCur, nxCur, src,
                                                     offp, eid, mpf, mpf + 512, blendH, z2I);

    // node update: nx' = act(concat(z2, nx) @ Wn)
    if (l < 4)
      gemmI<1024, true, true, false><<<gN, 256, 0, stream>>>(
          z2I, nxCur, WnT, 0, nxNxt, NNODES, nullptr, nullptr, nullptr, nullptr, nullptr);
    else
      gemmI<1024, true, false, false><<<gN, 256, 0, stream>>>(
          z2I, nxCur, WnT, 0, o_nx, NNODES, nullptr, nullptr, nullptr, nullptr, nullptr);

    // edge update: ex' = act(concat(blend, ex) @ We)
    if (l < 4)
      gemmI<1024, true, true, false><<<gE, 256, 0, stream>>>(
          blendH, exCur, WeT, 0, exNxt, NEDGES, nullptr, nullptr, nullptr, nullptr, nullptr);
    else
      gemmI<1024, true, false, false><<<gE, 256, 0, stream>>>(
          blendH, exCur, WeT, 0, o_ex, NEDGES, nullptr, nullptr, nullptr, nullptr, nullptr);
  }

  nodeconf_k<<<NNODES / 4, 256, 0, stream>>>(o_nx, Wnc, o_nc);
  edgeconf_k<<<NEDGES / 4, 256, 0, stream>>>(o_ex, Wec, o_ec);
}